// Round 1
// baseline (7123.489 us; speedup 1.0000x reference)
//
#include <hip/hip_runtime.h>
#include <cstddef>

// -------------------------------------------------------------------------
// GCN 3-layer forward: graph_conv -> BN+ReLU -> graph_conv -> BN+ReLU -> graph_conv
// Baseline: atomic scatter-add aggregation + f32 tiled dual-GEMM + 2-pass BN.
// -------------------------------------------------------------------------

// ---- edge aggregation: agg[dst] += x[src] * ew, F floats per node ----
template<int F>
__global__ void scatter_add_k(const float* __restrict__ x, const int* __restrict__ src,
                              const int* __restrict__ dst, const float* __restrict__ ew,
                              float* __restrict__ agg, int E) {
    const int TPE = F / 4;  // threads per edge (float4 each)
    int t = blockIdx.x * blockDim.x + threadIdx.x;
    int e = t / TPE;
    int f4 = t % TPE;
    if (e >= E) return;
    int s = src[e];
    int d = dst[e];
    float w = ew[e];
    float4 v = reinterpret_cast<const float4*>(x)[(size_t)s * TPE + f4];
    float* o = agg + (size_t)d * F + f4 * 4;
    atomicAdd(o + 0, v.x * w);
    atomicAdd(o + 1, v.y * w);
    atomicAdd(o + 2, v.z * w);
    atomicAdd(o + 3, v.w * w);
}

// ---- C[n,o] = sum_k A[n,k]*Wa[o,k] + sum_k X[n,k]*Wb[o,k] + bias[o] ----
// 64x64 output tile per block, 256 threads, 4x4 per thread, K-chunk 16.
__global__ void gemm_dual_k(const float* __restrict__ A, const float* __restrict__ Wa,
                            const float* __restrict__ X, const float* __restrict__ Wb,
                            const float* __restrict__ bias, float* __restrict__ C,
                            int Nrows, int K, int O) {
    __shared__ float As[16][68];  // +4 pad: 2-way max bank conflict, keeps 16B align
    __shared__ float Ws[16][68];
    const int tid = threadIdx.x;
    const int tx = tid & 15;      // output-col group
    const int ty = tid >> 4;      // output-row group
    const int lrow = tid >> 2;    // 0..63 loader row
    const int lkq  = tid & 3;     // 0..3 loader float4 within k-chunk
    const int m0 = blockIdx.x * 64;
    const int o0 = blockIdx.y * 64;

    float acc[4][4] = {};

    for (int phase = 0; phase < 2; ++phase) {
        const float* Ap = phase ? X : A;
        const float* Wp = phase ? Wb : Wa;
        for (int k0 = 0; k0 < K; k0 += 16) {
            // load 64x16 A tile + 64x16 W tile (k-major into LDS)
            float4 va = make_float4(0.f, 0.f, 0.f, 0.f);
            int gm = m0 + lrow;
            if (gm < Nrows)
                va = *reinterpret_cast<const float4*>(Ap + (size_t)gm * K + k0 + lkq * 4);
            float4 vw = *reinterpret_cast<const float4*>(Wp + (size_t)(o0 + lrow) * K + k0 + lkq * 4);
            __syncthreads();  // previous iteration's readers done
            As[lkq * 4 + 0][lrow] = va.x;
            As[lkq * 4 + 1][lrow] = va.y;
            As[lkq * 4 + 2][lrow] = va.z;
            As[lkq * 4 + 3][lrow] = va.w;
            Ws[lkq * 4 + 0][lrow] = vw.x;
            Ws[lkq * 4 + 1][lrow] = vw.y;
            Ws[lkq * 4 + 2][lrow] = vw.z;
            Ws[lkq * 4 + 3][lrow] = vw.w;
            __syncthreads();
            #pragma unroll
            for (int kk = 0; kk < 16; ++kk) {
                float4 av = *reinterpret_cast<const float4*>(&As[kk][ty * 4]);
                float4 bv = *reinterpret_cast<const float4*>(&Ws[kk][tx * 4]);
                float a[4] = {av.x, av.y, av.z, av.w};
                float b[4] = {bv.x, bv.y, bv.z, bv.w};
                #pragma unroll
                for (int i = 0; i < 4; ++i)
                    #pragma unroll
                    for (int j = 0; j < 4; ++j)
                        acc[i][j] += a[i] * b[j];
            }
        }
    }

    int gob = o0 + tx * 4;
    float4 bb = *reinterpret_cast<const float4*>(bias + gob);
    float bj[4] = {bb.x, bb.y, bb.z, bb.w};
    #pragma unroll
    for (int i = 0; i < 4; ++i) {
        int gm = m0 + ty * 4 + i;
        if (gm >= Nrows) break;
        float4 out = make_float4(acc[i][0] + bj[0], acc[i][1] + bj[1],
                                 acc[i][2] + bj[2], acc[i][3] + bj[3]);
        *reinterpret_cast<float4*>(C + (size_t)gm * O + gob) = out;
    }
}

// ---- BN stats: per-feature sum and sumsq over rows (F == blockDim.x == 256) ----
__global__ void bn_stats_k(const float* __restrict__ h, float* __restrict__ sums,
                           float* __restrict__ sumsq, int Nrows) {
    const int F = 256;
    int f = threadIdx.x;
    int r0 = blockIdx.x * 128;
    int r1 = min(r0 + 128, Nrows);
    float s = 0.f, q = 0.f;
    for (int r = r0; r < r1; ++r) {
        float v = h[(size_t)r * F + f];
        s += v;
        q += v * v;
    }
    atomicAdd(&sums[f], s);
    atomicAdd(&sumsq[f], q);
}

// ---- BN normalize + affine + ReLU, in place ----
__global__ void bn_relu_k(float* __restrict__ h, const float* __restrict__ sums,
                          const float* __restrict__ sumsq, const float* __restrict__ g,
                          const float* __restrict__ be, int Nrows) {
    const int F = 256;
    int t = blockIdx.x * blockDim.x + threadIdx.x;
    if (t >= Nrows * F) return;
    int f = t & (F - 1);
    float invN = 1.0f / (float)Nrows;
    float mu = sums[f] * invN;
    float var = sumsq[f] * invN - mu * mu;
    float inv = rsqrtf(var + 1e-5f);
    float v = (h[t] - mu) * inv * g[f] + be[f];
    h[t] = v > 0.f ? v : 0.f;
}

extern "C" void kernel_launch(void* const* d_in, const int* in_sizes, int n_in,
                              void* d_out, int out_size, void* d_ws, size_t ws_size,
                              hipStream_t stream) {
    const float* x   = (const float*)d_in[0];
    const int*   ei  = (const int*)d_in[1];
    const float* ew  = (const float*)d_in[2];
    const float* Wr0 = (const float*)d_in[3];
    const float* br0 = (const float*)d_in[4];
    const float* Wt0 = (const float*)d_in[5];
    const float* g0  = (const float*)d_in[6];
    const float* be0 = (const float*)d_in[7];
    const float* Wr1 = (const float*)d_in[8];
    const float* br1 = (const float*)d_in[9];
    const float* Wt1 = (const float*)d_in[10];
    const float* g1  = (const float*)d_in[11];
    const float* be1 = (const float*)d_in[12];
    const float* Wr2 = (const float*)d_in[13];
    const float* br2 = (const float*)d_in[14];
    const float* Wt2 = (const float*)d_in[15];

    const int E  = in_sizes[2];          // 800000
    const int Nn = in_sizes[0] / 128;    // 50000
    const int* src = ei;
    const int* dst = ei + E;

    float* agg   = (float*)d_ws;                       // Nn*256 floats (layer0 uses 128)
    float* h0    = agg + (size_t)Nn * 256;             // Nn*256
    float* h1    = h0 + (size_t)Nn * 256;              // Nn*256
    float* stats = h1 + (size_t)Nn * 256;              // 1024 floats
    float* out   = (float*)d_out;

    hipMemsetAsync(stats, 0, 1024 * sizeof(float), stream);

    dim3 blk(256);

    // ---------------- layer 0: K=128 -> 256 ----------------
    hipMemsetAsync(agg, 0, (size_t)Nn * 128 * sizeof(float), stream);
    {
        int threads = E * 32;
        scatter_add_k<128><<<dim3((threads + 255) / 256), blk, 0, stream>>>(x, src, dst, ew, agg, E);
    }
    {
        dim3 g((Nn + 63) / 64, 256 / 64);
        gemm_dual_k<<<g, blk, 0, stream>>>(agg, Wr0, x, Wt0, br0, h0, Nn, 128, 256);
    }
    bn_stats_k<<<dim3((Nn + 127) / 128), blk, 0, stream>>>(h0, stats + 0, stats + 256, Nn);
    bn_relu_k<<<dim3((Nn * 256 + 255) / 256), blk, 0, stream>>>(h0, stats + 0, stats + 256, g0, be0, Nn);

    // ---------------- layer 1: K=256 -> 256 ----------------
    hipMemsetAsync(agg, 0, (size_t)Nn * 256 * sizeof(float), stream);
    {
        int threads = E * 64;
        scatter_add_k<256><<<dim3((threads + 255) / 256), blk, 0, stream>>>(h0, src, dst, ew, agg, E);
    }
    {
        dim3 g((Nn + 63) / 64, 256 / 64);
        gemm_dual_k<<<g, blk, 0, stream>>>(agg, Wr1, h0, Wt1, br1, h1, Nn, 256, 256);
    }
    bn_stats_k<<<dim3((Nn + 127) / 128), blk, 0, stream>>>(h1, stats + 512, stats + 768, Nn);
    bn_relu_k<<<dim3((Nn * 256 + 255) / 256), blk, 0, stream>>>(h1, stats + 512, stats + 768, g1, be1, Nn);

    // ---------------- layer 2: K=256 -> 64 ----------------
    hipMemsetAsync(agg, 0, (size_t)Nn * 256 * sizeof(float), stream);
    {
        int threads = E * 64;
        scatter_add_k<256><<<dim3((threads + 255) / 256), blk, 0, stream>>>(h1, src, dst, ew, agg, E);
    }
    {
        dim3 g((Nn + 63) / 64, 64 / 64);
        gemm_dual_k<<<g, blk, 0, stream>>>(agg, Wr2, h1, Wt2, br2, out, Nn, 256, 64);
    }
}

// Round 2
// 895.362 us; speedup vs baseline: 7.9560x; 7.9560x over previous
//
#include <hip/hip_runtime.h>
#include <cstddef>

// -------------------------------------------------------------------------
// GCN 3-layer forward. Round 2: CSR-gather aggregation (no global atomics on
// feature data), f32 tiled dual-GEMM, 2-pass BN.
// -------------------------------------------------------------------------

#define SCAN_B 512

// ---- CSR build ----
__global__ void hist_k(const int* __restrict__ dst, int* __restrict__ counts, int E) {
    int e = blockIdx.x * blockDim.x + threadIdx.x;
    if (e < E) atomicAdd(&counts[dst[e]], 1);
}

__global__ void scan1_k(const int* __restrict__ counts, int* __restrict__ partial,
                        int* __restrict__ blocksum, int Nn) {
    __shared__ int sh[SCAN_B];
    int i = blockIdx.x * SCAN_B + threadIdx.x;
    int v = (i < Nn) ? counts[i] : 0;
    sh[threadIdx.x] = v;
    __syncthreads();
    for (int off = 1; off < SCAN_B; off <<= 1) {
        int t = (threadIdx.x >= (unsigned)off) ? sh[threadIdx.x - off] : 0;
        __syncthreads();
        sh[threadIdx.x] += t;
        __syncthreads();
    }
    if (i < Nn) partial[i] = sh[threadIdx.x];          // inclusive scan within block
    if (threadIdx.x == SCAN_B - 1) blocksum[blockIdx.x] = sh[threadIdx.x];
}

__global__ void scan2_k(int* __restrict__ blocksum, int nb) {
    __shared__ int sh[256];
    int v = (threadIdx.x < (unsigned)nb) ? blocksum[threadIdx.x] : 0;
    sh[threadIdx.x] = v;
    __syncthreads();
    for (int off = 1; off < 256; off <<= 1) {
        int t = (threadIdx.x >= (unsigned)off) ? sh[threadIdx.x - off] : 0;
        __syncthreads();
        sh[threadIdx.x] += t;
        __syncthreads();
    }
    if (threadIdx.x < (unsigned)nb) blocksum[threadIdx.x] = sh[threadIdx.x];
}

__global__ void scan3_k(const int* __restrict__ partial, const int* __restrict__ blocksum,
                        int* __restrict__ offsets, int Nn) {
    int i = blockIdx.x * SCAN_B + threadIdx.x;
    if (i >= Nn) return;
    int add = (blockIdx.x > 0) ? blocksum[blockIdx.x - 1] : 0;
    offsets[i + 1] = partial[i] + add;
    if (i == 0) offsets[0] = 0;
}

__global__ void fill_k(const int* __restrict__ src, const int* __restrict__ dst,
                       const float* __restrict__ ew, const int* __restrict__ offsets,
                       int* __restrict__ cursor, int* __restrict__ e_src,
                       float* __restrict__ e_w, int E) {
    int e = blockIdx.x * blockDim.x + threadIdx.x;
    if (e >= E) return;
    int d = dst[e];
    int pos = offsets[d] + atomicAdd(&cursor[d], 1);
    e_src[pos] = src[e];
    e_w[pos] = ew[e];
}

// ---- aggregation: one wave per destination node, gather + accumulate ----
template<int F>
__global__ void gather_k(const float* __restrict__ x, const int* __restrict__ offsets,
                         const int* __restrict__ e_src, const float* __restrict__ e_w,
                         float* __restrict__ agg, int Nn) {
    const int VEC = F / 64;   // floats per lane
    int wid = (blockIdx.x * blockDim.x + threadIdx.x) >> 6;  // node id
    int lane = threadIdx.x & 63;
    if (wid >= Nn) return;
    int beg = offsets[wid], end = offsets[wid + 1];
    if constexpr (VEC == 4) {
        float4 acc = make_float4(0.f, 0.f, 0.f, 0.f);
        for (int p = beg; p < end; ++p) {
            int s = e_src[p];
            float w = e_w[p];
            float4 v = *reinterpret_cast<const float4*>(x + (size_t)s * F + lane * 4);
            acc.x += w * v.x; acc.y += w * v.y; acc.z += w * v.z; acc.w += w * v.w;
        }
        *reinterpret_cast<float4*>(agg + (size_t)wid * F + lane * 4) = acc;
    } else {
        float2 acc = make_float2(0.f, 0.f);
        for (int p = beg; p < end; ++p) {
            int s = e_src[p];
            float w = e_w[p];
            float2 v = *reinterpret_cast<const float2*>(x + (size_t)s * F + lane * 2);
            acc.x += w * v.x; acc.y += w * v.y;
        }
        *reinterpret_cast<float2*>(agg + (size_t)wid * F + lane * 2) = acc;
    }
}

// ---- C[n,o] = sum_k A[n,k]*Wa[o,k] + sum_k X[n,k]*Wb[o,k] + bias[o] ----
__global__ void gemm_dual_k(const float* __restrict__ A, const float* __restrict__ Wa,
                            const float* __restrict__ X, const float* __restrict__ Wb,
                            const float* __restrict__ bias, float* __restrict__ C,
                            int Nrows, int K, int O) {
    __shared__ float As[16][68];
    __shared__ float Ws[16][68];
    const int tid = threadIdx.x;
    const int tx = tid & 15;
    const int ty = tid >> 4;
    const int lrow = tid >> 2;
    const int lkq  = tid & 3;
    const int m0 = blockIdx.x * 64;
    const int o0 = blockIdx.y * 64;

    float acc[4][4] = {};

    for (int phase = 0; phase < 2; ++phase) {
        const float* Ap = phase ? X : A;
        const float* Wp = phase ? Wb : Wa;
        for (int k0 = 0; k0 < K; k0 += 16) {
            float4 va = make_float4(0.f, 0.f, 0.f, 0.f);
            int gm = m0 + lrow;
            if (gm < Nrows)
                va = *reinterpret_cast<const float4*>(Ap + (size_t)gm * K + k0 + lkq * 4);
            float4 vw = *reinterpret_cast<const float4*>(Wp + (size_t)(o0 + lrow) * K + k0 + lkq * 4);
            __syncthreads();
            As[lkq * 4 + 0][lrow] = va.x;
            As[lkq * 4 + 1][lrow] = va.y;
            As[lkq * 4 + 2][lrow] = va.z;
            As[lkq * 4 + 3][lrow] = va.w;
            Ws[lkq * 4 + 0][lrow] = vw.x;
            Ws[lkq * 4 + 1][lrow] = vw.y;
            Ws[lkq * 4 + 2][lrow] = vw.z;
            Ws[lkq * 4 + 3][lrow] = vw.w;
            __syncthreads();
            #pragma unroll
            for (int kk = 0; kk < 16; ++kk) {
                float4 av = *reinterpret_cast<const float4*>(&As[kk][ty * 4]);
                float4 bv = *reinterpret_cast<const float4*>(&Ws[kk][tx * 4]);
                float a[4] = {av.x, av.y, av.z, av.w};
                float b[4] = {bv.x, bv.y, bv.z, bv.w};
                #pragma unroll
                for (int i = 0; i < 4; ++i)
                    #pragma unroll
                    for (int j = 0; j < 4; ++j)
                        acc[i][j] += a[i] * b[j];
            }
        }
    }

    int gob = o0 + tx * 4;
    float4 bb = *reinterpret_cast<const float4*>(bias + gob);
    float bj[4] = {bb.x, bb.y, bb.z, bb.w};
    #pragma unroll
    for (int i = 0; i < 4; ++i) {
        int gm = m0 + ty * 4 + i;
        if (gm >= Nrows) break;
        float4 out = make_float4(acc[i][0] + bj[0], acc[i][1] + bj[1],
                                 acc[i][2] + bj[2], acc[i][3] + bj[3]);
        *reinterpret_cast<float4*>(C + (size_t)gm * O + gob) = out;
    }
}

// ---- BN stats ----
__global__ void bn_stats_k(const float* __restrict__ h, float* __restrict__ sums,
                           float* __restrict__ sumsq, int Nrows) {
    const int F = 256;
    int f = threadIdx.x;
    int r0 = blockIdx.x * 128;
    int r1 = min(r0 + 128, Nrows);
    float s = 0.f, q = 0.f;
    for (int r = r0; r < r1; ++r) {
        float v = h[(size_t)r * F + f];
        s += v;
        q += v * v;
    }
    atomicAdd(&sums[f], s);
    atomicAdd(&sumsq[f], q);
}

// ---- BN normalize + affine + ReLU, in place ----
__global__ void bn_relu_k(float* __restrict__ h, const float* __restrict__ sums,
                          const float* __restrict__ sumsq, const float* __restrict__ g,
                          const float* __restrict__ be, int Nrows) {
    const int F = 256;
    int t = blockIdx.x * blockDim.x + threadIdx.x;
    if (t >= Nrows * F) return;
    int f = t & (F - 1);
    float invN = 1.0f / (float)Nrows;
    float mu = sums[f] * invN;
    float var = sumsq[f] * invN - mu * mu;
    float inv = rsqrtf(var + 1e-5f);
    float v = (h[t] - mu) * inv * g[f] + be[f];
    h[t] = v > 0.f ? v : 0.f;
}

extern "C" void kernel_launch(void* const* d_in, const int* in_sizes, int n_in,
                              void* d_out, int out_size, void* d_ws, size_t ws_size,
                              hipStream_t stream) {
    const float* x   = (const float*)d_in[0];
    const int*   ei  = (const int*)d_in[1];
    const float* ew  = (const float*)d_in[2];
    const float* Wr0 = (const float*)d_in[3];
    const float* br0 = (const float*)d_in[4];
    const float* Wt0 = (const float*)d_in[5];
    const float* g0  = (const float*)d_in[6];
    const float* be0 = (const float*)d_in[7];
    const float* Wr1 = (const float*)d_in[8];
    const float* br1 = (const float*)d_in[9];
    const float* Wt1 = (const float*)d_in[10];
    const float* g1  = (const float*)d_in[11];
    const float* be1 = (const float*)d_in[12];
    const float* Wr2 = (const float*)d_in[13];
    const float* br2 = (const float*)d_in[14];
    const float* Wt2 = (const float*)d_in[15];

    const int E  = in_sizes[2];          // 800000
    const int Nn = in_sizes[0] / 128;    // 50000
    const int* src = ei;
    const int* dst = ei + E;

    // ---- workspace layout ----
    float* agg   = (float*)d_ws;                         // Nn*256 f
    float* h0    = agg + (size_t)Nn * 256;               // Nn*256 f
    float* h1    = h0 + (size_t)Nn * 256;                // Nn*256 f
    float* stats = h1 + (size_t)Nn * 256;                // 1024 f
    float* e_w   = stats + 1024;                         // E f
    int*   e_src = (int*)(e_w + E);                      // E i
    int*   offsets = e_src + E;                          // Nn+1 i
    int*   counts  = offsets + Nn + 1;                   // Nn i (aliased as cursor later)
    int*   partial = counts + Nn;                        // Nn i
    int*   blocksum = partial + Nn;                      // 256 i

    dim3 blk(256);
    const int nbScan = (Nn + SCAN_B - 1) / SCAN_B;

    // ---- CSR build (once; shared by all 3 layers) ----
    hipMemsetAsync(counts, 0, (size_t)Nn * sizeof(int), stream);
    hist_k<<<dim3((E + 255) / 256), blk, 0, stream>>>(dst, counts, E);
    scan1_k<<<dim3(nbScan), dim3(SCAN_B), 0, stream>>>(counts, partial, blocksum, Nn);
    scan2_k<<<dim3(1), dim3(256), 0, stream>>>(blocksum, nbScan);
    scan3_k<<<dim3(nbScan), dim3(SCAN_B), 0, stream>>>(partial, blocksum, offsets, Nn);
    hipMemsetAsync(counts, 0, (size_t)Nn * sizeof(int), stream);  // reuse as cursor
    fill_k<<<dim3((E + 255) / 256), blk, 0, stream>>>(src, dst, ew, offsets, counts, e_src, e_w, E);

    hipMemsetAsync(stats, 0, 1024 * sizeof(float), stream);

    const int gatherBlocks = (Nn * 64 + 255) / 256;

    // ---------------- layer 0: K=128 -> 256 ----------------
    gather_k<128><<<dim3(gatherBlocks), blk, 0, stream>>>(x, offsets, e_src, e_w, agg, Nn);
    {
        dim3 g((Nn + 63) / 64, 256 / 64);
        gemm_dual_k<<<g, blk, 0, stream>>>(agg, Wr0, x, Wt0, br0, h0, Nn, 128, 256);
    }
    bn_stats_k<<<dim3((Nn + 127) / 128), blk, 0, stream>>>(h0, stats + 0, stats + 256, Nn);
    bn_relu_k<<<dim3((Nn * 256 + 255) / 256), blk, 0, stream>>>(h0, stats + 0, stats + 256, g0, be0, Nn);

    // ---------------- layer 1: K=256 -> 256 ----------------
    gather_k<256><<<dim3(gatherBlocks), blk, 0, stream>>>(h0, offsets, e_src, e_w, agg, Nn);
    {
        dim3 g((Nn + 63) / 64, 256 / 64);
        gemm_dual_k<<<g, blk, 0, stream>>>(agg, Wr1, h0, Wt1, br1, h1, Nn, 256, 256);
    }
    bn_stats_k<<<dim3((Nn + 127) / 128), blk, 0, stream>>>(h1, stats + 512, stats + 768, Nn);
    bn_relu_k<<<dim3((Nn * 256 + 255) / 256), blk, 0, stream>>>(h1, stats + 512, stats + 768, g1, be1, Nn);

    // ---------------- layer 2: K=256 -> 64 ----------------
    gather_k<256><<<dim3(gatherBlocks), blk, 0, stream>>>(h1, offsets, e_src, e_w, agg, Nn);
    {
        dim3 g((Nn + 63) / 64, 1);
        gemm_dual_k<<<g, blk, 0, stream>>>(agg, Wr2, h1, Wt2, br2, (float*)d_out, Nn, 256, 64);
    }
}

// Round 3
// 586.913 us; speedup vs baseline: 12.1372x; 1.5255x over previous
//
#include <hip/hip_runtime.h>
#include <cstddef>
#include <cstdint>

#define SCAN_B 512

using bf16x8 = __attribute__((ext_vector_type(8))) short;
using f32x4  = __attribute__((ext_vector_type(4))) float;

__device__ __forceinline__ unsigned short f2bf(float f) {
    unsigned int u = __builtin_bit_cast(unsigned int, f);
    return (unsigned short)((u + 0x7FFFu + ((u >> 16) & 1u)) >> 16);  // RNE
}
__device__ __forceinline__ float bf2f(unsigned short b) {
    unsigned int u = ((unsigned int)b) << 16;
    return __builtin_bit_cast(float, u);
}
__device__ __forceinline__ void gload_lds16(const void* g, void* l) {
    __builtin_amdgcn_global_load_lds((const __attribute__((address_space(1))) void*)g,
                                     (__attribute__((address_space(3))) void*)l, 16, 0, 0);
}

// ---------------- CSR build ----------------
__global__ void hist_k(const int* __restrict__ dst, int* __restrict__ counts, int E) {
    int e = blockIdx.x * blockDim.x + threadIdx.x;
    if (e < E) atomicAdd(&counts[dst[e]], 1);
}

__global__ void scan1_k(const int* __restrict__ counts, int* __restrict__ partial,
                        int* __restrict__ blocksum, int Nn) {
    __shared__ int sh[SCAN_B];
    int i = blockIdx.x * SCAN_B + threadIdx.x;
    int v = (i < Nn) ? counts[i] : 0;
    sh[threadIdx.x] = v;
    __syncthreads();
    for (int off = 1; off < SCAN_B; off <<= 1) {
        int t = (threadIdx.x >= (unsigned)off) ? sh[threadIdx.x - off] : 0;
        __syncthreads();
        sh[threadIdx.x] += t;
        __syncthreads();
    }
    if (i < Nn) partial[i] = sh[threadIdx.x];
    if (threadIdx.x == SCAN_B - 1) blocksum[blockIdx.x] = sh[threadIdx.x];
}

__global__ void scan2_k(int* __restrict__ blocksum, int nb) {
    __shared__ int sh[256];
    int v = (threadIdx.x < (unsigned)nb) ? blocksum[threadIdx.x] : 0;
    sh[threadIdx.x] = v;
    __syncthreads();
    for (int off = 1; off < 256; off <<= 1) {
        int t = (threadIdx.x >= (unsigned)off) ? sh[threadIdx.x - off] : 0;
        __syncthreads();
        sh[threadIdx.x] += t;
        __syncthreads();
    }
    if (threadIdx.x < (unsigned)nb) blocksum[threadIdx.x] = sh[threadIdx.x];
}

__global__ void scan3_k(const int* __restrict__ partial, const int* __restrict__ blocksum,
                        int* __restrict__ offsets, int Nn) {
    int i = blockIdx.x * SCAN_B + threadIdx.x;
    if (i >= Nn) return;
    int add = (blockIdx.x > 0) ? blocksum[blockIdx.x - 1] : 0;
    offsets[i + 1] = partial[i] + add;
    if (i == 0) offsets[0] = 0;
}

__global__ void fill_k(const int* __restrict__ src, const int* __restrict__ dst,
                       const float* __restrict__ ew, const int* __restrict__ offsets,
                       int* __restrict__ cursor, int* __restrict__ e_src,
                       float* __restrict__ e_w, int E) {
    int e = blockIdx.x * blockDim.x + threadIdx.x;
    if (e >= E) return;
    int d = dst[e];
    int pos = offsets[d] + atomicAdd(&cursor[d], 1);
    e_src[pos] = src[e];
    e_w[pos] = ew[e];
}

// ---------------- f32 -> bf16 convert ----------------
__global__ void f2bf_k(const float* __restrict__ src, unsigned short* __restrict__ dst, int n4) {
    int i = blockIdx.x * blockDim.x + threadIdx.x;
    if (i >= n4) return;
    float4 v = reinterpret_cast<const float4*>(src)[i];
    ushort4 o;
    o.x = f2bf(v.x); o.y = f2bf(v.y); o.z = f2bf(v.z); o.w = f2bf(v.w);
    reinterpret_cast<ushort4*>(dst)[i] = o;
}

// ---------------- gather (CSR, bf16 in/out, f32 accumulate) ----------------
template<int F>
__global__ void gather_bf_k(const unsigned short* __restrict__ x, const int* __restrict__ offsets,
                            const int* __restrict__ e_src, const float* __restrict__ e_w,
                            unsigned short* __restrict__ agg, int Nn) {
    int wid = (blockIdx.x * blockDim.x + threadIdx.x) >> 6;
    int lane = threadIdx.x & 63;
    if (wid >= Nn) return;
    int beg = offsets[wid], end = offsets[wid + 1];
    if constexpr (F == 256) {
        float a0 = 0.f, a1 = 0.f, a2 = 0.f, a3 = 0.f;
        for (int p = beg; p < end; ++p) {
            int s = e_src[p];
            float w = e_w[p];
            ushort4 v = *reinterpret_cast<const ushort4*>(x + (size_t)s * F + lane * 4);
            a0 += w * bf2f(v.x); a1 += w * bf2f(v.y);
            a2 += w * bf2f(v.z); a3 += w * bf2f(v.w);
        }
        ushort4 o;
        o.x = f2bf(a0); o.y = f2bf(a1); o.z = f2bf(a2); o.w = f2bf(a3);
        *reinterpret_cast<ushort4*>(agg + (size_t)wid * F + lane * 4) = o;
    } else {
        float a0 = 0.f, a1 = 0.f;
        for (int p = beg; p < end; ++p) {
            int s = e_src[p];
            float w = e_w[p];
            unsigned int v = *reinterpret_cast<const unsigned int*>(x + (size_t)s * F + lane * 2);
            a0 += w * bf2f((unsigned short)(v & 0xFFFFu));
            a1 += w * bf2f((unsigned short)(v >> 16));
        }
        unsigned int o = (unsigned int)f2bf(a0) | ((unsigned int)f2bf(a1) << 16);
        *reinterpret_cast<unsigned int*>(agg + (size_t)wid * F + lane * 2) = o;
    }
}

// ---------------- bf16 MFMA dual-GEMM ----------------
// C[n,o] = sum_k A[n,k]Wa[o,k] + sum_k X[n,k]Wb[o,k] + bias[o]
// BM x O tile, 256 threads / 4 waves; wave tile (BM/WM) x (O/WN); BK=64.
// LDS layout: row-major [rows][64] ushort with 16B-slot XOR swizzle (slot ^= row&7),
// realized as linear LDS dest + pre-swizzled global source (global_load_lds rule).
template<int K, int O, int BM, int WM, int WN>
__global__ __launch_bounds__(256) void gemm_mfma_k(
        const unsigned short* __restrict__ A, const unsigned short* __restrict__ Wa,
        const unsigned short* __restrict__ X, const unsigned short* __restrict__ Wb,
        const float* __restrict__ bias, float* __restrict__ C, int Nn) {
    constexpr int MI = BM / (WM * 16);
    constexpr int OJ = O / (WN * 16);
    constexpr int ACH = BM / 32;   // 16B chunks per thread for A tile (BM*128B / 256 / 16)
    constexpr int BCH = O / 32;
    __shared__ unsigned short As[BM * 64];
    __shared__ unsigned short Bs[O * 64];
    const int tid = threadIdx.x;
    const int w = tid >> 6, l = tid & 63;
    const int wm = w / WN, wn = w % WN;
    const int lrow = l & 15, kgrp = l >> 4;
    const int m0 = blockIdx.x * BM;

    f32x4 acc[MI][OJ];
    #pragma unroll
    for (int i = 0; i < MI; ++i)
        #pragma unroll
        for (int j = 0; j < OJ; ++j) {
            f32x4 z = {0.f, 0.f, 0.f, 0.f};
            acc[i][j] = z;
        }

    for (int phase = 0; phase < 2; ++phase) {
        const unsigned short* Ap = phase ? X : A;
        const unsigned short* Wp = phase ? Wb : Wa;
        for (int k0 = 0; k0 < K; k0 += 64) {
            __syncthreads();   // previous iteration's ds_reads done
            #pragma unroll
            for (int i = 0; i < ACH; ++i) {
                int c = i * 256 + tid;
                int row = c >> 3, slot = c & 7;
                gload_lds16(Ap + (size_t)(m0 + row) * K + k0 + ((slot ^ (row & 7)) << 3),
                            &As[(i * 256 + w * 64) * 8]);
            }
            #pragma unroll
            for (int i = 0; i < BCH; ++i) {
                int c = i * 256 + tid;
                int row = c >> 3, slot = c & 7;
                gload_lds16(Wp + (size_t)row * K + k0 + ((slot ^ (row & 7)) << 3),
                            &Bs[(i * 256 + w * 64) * 8]);
            }
            __syncthreads();   // compiler drains vmcnt before barrier -> LDS ready
            #pragma unroll
            for (int ks = 0; ks < 2; ++ks) {
                bf16x8 a[MI], b[OJ];
                #pragma unroll
                for (int mi = 0; mi < MI; ++mi) {
                    int row = wm * (MI * 16) + mi * 16 + lrow;
                    int slot = (ks * 4 + kgrp) ^ (row & 7);
                    a[mi] = *reinterpret_cast<const bf16x8*>(&As[row * 64 + slot * 8]);
                }
                #pragma unroll
                for (int oj = 0; oj < OJ; ++oj) {
                    int row = wn * (OJ * 16) + oj * 16 + lrow;
                    int slot = (ks * 4 + kgrp) ^ (row & 7);
                    b[oj] = *reinterpret_cast<const bf16x8*>(&Bs[row * 64 + slot * 8]);
                }
                #pragma unroll
                for (int mi = 0; mi < MI; ++mi)
                    #pragma unroll
                    for (int oj = 0; oj < OJ; ++oj)
                        acc[mi][oj] = __builtin_amdgcn_mfma_f32_16x16x32_bf16(
                            a[mi], b[oj], acc[mi][oj], 0, 0, 0);
            }
        }
    }

    #pragma unroll
    for (int mi = 0; mi < MI; ++mi) {
        #pragma unroll
        for (int r = 0; r < 4; ++r) {
            int row = m0 + wm * (MI * 16) + mi * 16 + kgrp * 4 + r;
            if (row < Nn) {
                #pragma unroll
                for (int oj = 0; oj < OJ; ++oj) {
                    int col = wn * (OJ * 16) + oj * 16 + lrow;
                    C[(size_t)row * O + col] = acc[mi][oj][r] + bias[col];
                }
            }
        }
    }
}

// ---------------- BN ----------------
__global__ void bn_stats_k(const float* __restrict__ h, float* __restrict__ sums,
                           float* __restrict__ sumsq, int Nrows) {
    const int F = 256;
    int f = threadIdx.x;
    int r0 = blockIdx.x * 128;
    int r1 = min(r0 + 128, Nrows);
    float s = 0.f, q = 0.f;
    for (int r = r0; r < r1; ++r) {
        float v = h[(size_t)r * F + f];
        s += v;
        q += v * v;
    }
    atomicAdd(&sums[f], s);
    atomicAdd(&sumsq[f], q);
}

// normalize + affine + relu; read f32, write bf16 (input to next layer)
__global__ void bn_relu_bf_k(const float* __restrict__ h, const float* __restrict__ sums,
                             const float* __restrict__ sumsq, const float* __restrict__ g,
                             const float* __restrict__ be, unsigned short* __restrict__ hb,
                             int Nrows) {
    const int F = 256;
    int t = blockIdx.x * blockDim.x + threadIdx.x;   // float4 index
    if (t >= Nrows * (F / 4)) return;
    int f0 = (t & 63) * 4;
    float invN = 1.0f / (float)Nrows;
    float4 v = reinterpret_cast<const float4*>(h)[t];
    float vv[4] = {v.x, v.y, v.z, v.w};
    ushort4 o;
    unsigned short* op = &o.x;
    #pragma unroll
    for (int c = 0; c < 4; ++c) {
        int f = f0 + c;
        float mu = sums[f] * invN;
        float var = sumsq[f] * invN - mu * mu;
        float inv = rsqrtf(var + 1e-5f);
        float r = (vv[c] - mu) * inv * g[f] + be[f];
        op[c] = f2bf(r > 0.f ? r : 0.f);
    }
    reinterpret_cast<ushort4*>(hb)[t] = o;
}

extern "C" void kernel_launch(void* const* d_in, const int* in_sizes, int n_in,
                              void* d_out, int out_size, void* d_ws, size_t ws_size,
                              hipStream_t stream) {
    const float* x   = (const float*)d_in[0];
    const int*   ei  = (const int*)d_in[1];
    const float* ew  = (const float*)d_in[2];
    const float* Wr0 = (const float*)d_in[3];
    const float* br0 = (const float*)d_in[4];
    const float* Wt0 = (const float*)d_in[5];
    const float* g0  = (const float*)d_in[6];
    const float* be0 = (const float*)d_in[7];
    const float* Wr1 = (const float*)d_in[8];
    const float* br1 = (const float*)d_in[9];
    const float* Wt1 = (const float*)d_in[10];
    const float* g1  = (const float*)d_in[11];
    const float* be1 = (const float*)d_in[12];
    const float* Wr2 = (const float*)d_in[13];
    const float* br2 = (const float*)d_in[14];
    const float* Wt2 = (const float*)d_in[15];

    const int E  = in_sizes[2];          // 800000
    const int Nn = in_sizes[0] / 128;    // 50000
    const size_t NP = 50176;             // padded rows (multiple of 256)
    const int* src = ei;
    const int* dst = ei + E;

    // ---- workspace layout (elements) ----
    unsigned short* x_bf   = (unsigned short*)d_ws;        // NP*128
    unsigned short* agg_bf = x_bf + NP * 128;              // NP*256
    unsigned short* h0_bf  = agg_bf + NP * 256;            // NP*256
    unsigned short* h1_bf  = h0_bf + NP * 256;             // NP*256
    unsigned short* wbf    = h1_bf + NP * 256;             // 229376
    unsigned short* Wr0b = wbf;
    unsigned short* Wt0b = wbf + 32768;
    unsigned short* Wr1b = wbf + 65536;
    unsigned short* Wt1b = wbf + 131072;
    unsigned short* Wr2b = wbf + 196608;
    unsigned short* Wt2b = wbf + 212992;
    float* h_f32 = (float*)(wbf + 229376);                 // Nn*256
    float* stats = h_f32 + (size_t)Nn * 256;               // 1024
    float* e_w   = stats + 1024;                           // E
    int*   e_src = (int*)(e_w + E);                        // E
    int*   offsets = e_src + E;                            // Nn+1
    int*   counts  = offsets + Nn + 1;                     // Nn (reused as cursor)
    int*   partial = counts + Nn;                          // Nn
    int*   blocksum = partial + Nn;                        // 256

    dim3 blk(256);
    const int nbScan = (Nn + SCAN_B - 1) / SCAN_B;

    // ---- CSR build ----
    hipMemsetAsync(counts, 0, (size_t)Nn * sizeof(int), stream);
    hist_k<<<dim3((E + 255) / 256), blk, 0, stream>>>(dst, counts, E);
    scan1_k<<<dim3(nbScan), dim3(SCAN_B), 0, stream>>>(counts, partial, blocksum, Nn);
    scan2_k<<<dim3(1), dim3(256), 0, stream>>>(blocksum, nbScan);
    scan3_k<<<dim3(nbScan), dim3(SCAN_B), 0, stream>>>(partial, blocksum, offsets, Nn);
    hipMemsetAsync(counts, 0, (size_t)Nn * sizeof(int), stream);
    fill_k<<<dim3((E + 255) / 256), blk, 0, stream>>>(src, dst, ew, offsets, counts, e_src, e_w, E);

    // ---- conversions ----
    f2bf_k<<<dim3((Nn * 128 / 4 + 255) / 256), blk, 0, stream>>>(x, x_bf, Nn * 128 / 4);
    f2bf_k<<<dim3(32), blk, 0, stream>>>(Wr0, Wr0b, 8192);
    f2bf_k<<<dim3(32), blk, 0, stream>>>(Wt0, Wt0b, 8192);
    f2bf_k<<<dim3(64), blk, 0, stream>>>(Wr1, Wr1b, 16384);
    f2bf_k<<<dim3(64), blk, 0, stream>>>(Wt1, Wt1b, 16384);
    f2bf_k<<<dim3(16), blk, 0, stream>>>(Wr2, Wr2b, 4096);
    f2bf_k<<<dim3(16), blk, 0, stream>>>(Wt2, Wt2b, 4096);

    hipMemsetAsync(stats, 0, 1024 * sizeof(float), stream);

    const int gatherBlocks = (Nn * 64 + 255) / 256;

    // ---------------- layer 0: K=128 -> 256 ----------------
    gather_bf_k<128><<<dim3(gatherBlocks), blk, 0, stream>>>(x_bf, offsets, e_src, e_w, agg_bf, Nn);
    gemm_mfma_k<128, 256, 128, 1, 4><<<dim3(NP / 128), blk, 0, stream>>>(
        agg_bf, Wr0b, x_bf, Wt0b, br0, h_f32, Nn);
    bn_stats_k<<<dim3((Nn + 127) / 128), blk, 0, stream>>>(h_f32, stats + 0, stats + 256, Nn);
    bn_relu_bf_k<<<dim3((Nn * 64 + 255) / 256), blk, 0, stream>>>(
        h_f32, stats + 0, stats + 256, g0, be0, h0_bf, Nn);

    // ---------------- layer 1: K=256 -> 256 ----------------
    gather_bf_k<256><<<dim3(gatherBlocks), blk, 0, stream>>>(h0_bf, offsets, e_src, e_w, agg_bf, Nn);
    gemm_mfma_k<256, 256, 128, 1, 4><<<dim3(NP / 128), blk, 0, stream>>>(
        agg_bf, Wr1b, h0_bf, Wt1b, br1, h_f32, Nn);
    bn_stats_k<<<dim3((Nn + 127) / 128), blk, 0, stream>>>(h_f32, stats + 512, stats + 768, Nn);
    bn_relu_bf_k<<<dim3((Nn * 64 + 255) / 256), blk, 0, stream>>>(
        h_f32, stats + 512, stats + 768, g1, be1, h1_bf, Nn);

    // ---------------- layer 2: K=256 -> 64 ----------------
    gather_bf_k<256><<<dim3(gatherBlocks), blk, 0, stream>>>(h1_bf, offsets, e_src, e_w, agg_bf, Nn);
    gemm_mfma_k<256, 64, 256, 4, 1><<<dim3(NP / 256), blk, 0, stream>>>(
        agg_bf, Wr2b, h1_bf, Wt2b, br2, (float*)d_out, Nn);
}

// Round 4
// 395.466 us; speedup vs baseline: 18.0129x; 1.4841x over previous
//
#include <hip/hip_runtime.h>
#include <cstddef>
#include <cstdint>

#define SCAN_B 512

using bf16x8 = __attribute__((ext_vector_type(8))) short;
using f32x4  = __attribute__((ext_vector_type(4))) float;

__device__ __forceinline__ unsigned short f2bf(float f) {
    unsigned int u = __builtin_bit_cast(unsigned int, f);
    return (unsigned short)((u + 0x7FFFu + ((u >> 16) & 1u)) >> 16);  // RNE
}
__device__ __forceinline__ float bf2f(unsigned short b) {
    unsigned int u = ((unsigned int)b) << 16;
    return __builtin_bit_cast(float, u);
}
__device__ __forceinline__ float i2f(int i) { return __builtin_bit_cast(float, i); }
__device__ __forceinline__ void gload_lds16(const void* g, void* l) {
    __builtin_amdgcn_global_load_lds((const __attribute__((address_space(1))) void*)g,
                                     (__attribute__((address_space(3))) void*)l, 16, 0, 0);
}

// ---------------- CSR build ----------------
__global__ void hist_k(const int* __restrict__ dst, int* __restrict__ counts, int E) {
    int e = blockIdx.x * blockDim.x + threadIdx.x;
    if (e < E) atomicAdd(&counts[dst[e]], 1);
}

__global__ void scan1_k(const int* __restrict__ counts, int* __restrict__ partial,
                        int* __restrict__ blocksum, int Nn) {
    __shared__ int sh[SCAN_B];
    int i = blockIdx.x * SCAN_B + threadIdx.x;
    int v = (i < Nn) ? counts[i] : 0;
    sh[threadIdx.x] = v;
    __syncthreads();
    for (int off = 1; off < SCAN_B; off <<= 1) {
        int t = (threadIdx.x >= (unsigned)off) ? sh[threadIdx.x - off] : 0;
        __syncthreads();
        sh[threadIdx.x] += t;
        __syncthreads();
    }
    if (i < Nn) partial[i] = sh[threadIdx.x];
    if (threadIdx.x == SCAN_B - 1) blocksum[blockIdx.x] = sh[threadIdx.x];
}

__global__ void scan2_k(int* __restrict__ blocksum, int nb) {
    __shared__ int sh[256];
    int v = (threadIdx.x < (unsigned)nb) ? blocksum[threadIdx.x] : 0;
    sh[threadIdx.x] = v;
    __syncthreads();
    for (int off = 1; off < 256; off <<= 1) {
        int t = (threadIdx.x >= (unsigned)off) ? sh[threadIdx.x - off] : 0;
        __syncthreads();
        sh[threadIdx.x] += t;
        __syncthreads();
    }
    if (threadIdx.x < (unsigned)nb) blocksum[threadIdx.x] = sh[threadIdx.x];
}

__global__ void scan3_k(const int* __restrict__ partial, const int* __restrict__ blocksum,
                        int* __restrict__ offsets, int Nn) {
    int i = blockIdx.x * SCAN_B + threadIdx.x;
    if (i >= Nn) return;
    int add = (blockIdx.x > 0) ? blocksum[blockIdx.x - 1] : 0;
    offsets[i + 1] = partial[i] + add;
    if (i == 0) offsets[0] = 0;
}

__global__ void fill_k(const int* __restrict__ src, const int* __restrict__ dst,
                       const float* __restrict__ ew, const int* __restrict__ offsets,
                       int* __restrict__ cursor, int2* __restrict__ e_sw, int E) {
    int e = blockIdx.x * blockDim.x + threadIdx.x;
    if (e >= E) return;
    int d = dst[e];
    int pos = offsets[d] + atomicAdd(&cursor[d], 1);
    e_sw[pos] = make_int2(src[e], __builtin_bit_cast(int, ew[e]));
}

// ---------------- f32 -> bf16 convert ----------------
__global__ void f2bf_k(const float* __restrict__ src, unsigned short* __restrict__ dst, int n4) {
    int i = blockIdx.x * blockDim.x + threadIdx.x;
    if (i >= n4) return;
    float4 v = reinterpret_cast<const float4*>(src)[i];
    ushort4 o;
    o.x = f2bf(v.x); o.y = f2bf(v.y); o.z = f2bf(v.z); o.w = f2bf(v.w);
    reinterpret_cast<ushort4*>(dst)[i] = o;
}

// ---------------- gather (CSR, bf16 in/out, f32 acc, 4-way pipelined) ----------------
template<int F>
__global__ void gather_bf_k(const unsigned short* __restrict__ x, const int* __restrict__ offsets,
                            const int2* __restrict__ e_sw, unsigned short* __restrict__ agg, int Nn) {
    int wid = (blockIdx.x * blockDim.x + threadIdx.x) >> 6;
    int lane = threadIdx.x & 63;
    if (wid >= Nn) return;
    int p = offsets[wid], end = offsets[wid + 1];
    if constexpr (F == 256) {
        float a0 = 0.f, a1 = 0.f, a2 = 0.f, a3 = 0.f;
        for (; p + 4 <= end; p += 4) {
            int2 e0 = e_sw[p], e1 = e_sw[p + 1], e2 = e_sw[p + 2], e3 = e_sw[p + 3];
            ushort4 v0 = *reinterpret_cast<const ushort4*>(x + (size_t)e0.x * F + lane * 4);
            ushort4 v1 = *reinterpret_cast<const ushort4*>(x + (size_t)e1.x * F + lane * 4);
            ushort4 v2 = *reinterpret_cast<const ushort4*>(x + (size_t)e2.x * F + lane * 4);
            ushort4 v3 = *reinterpret_cast<const ushort4*>(x + (size_t)e3.x * F + lane * 4);
            float w0 = i2f(e0.y), w1 = i2f(e1.y), w2 = i2f(e2.y), w3 = i2f(e3.y);
            a0 += w0 * bf2f(v0.x) + w1 * bf2f(v1.x) + w2 * bf2f(v2.x) + w3 * bf2f(v3.x);
            a1 += w0 * bf2f(v0.y) + w1 * bf2f(v1.y) + w2 * bf2f(v2.y) + w3 * bf2f(v3.y);
            a2 += w0 * bf2f(v0.z) + w1 * bf2f(v1.z) + w2 * bf2f(v2.z) + w3 * bf2f(v3.z);
            a3 += w0 * bf2f(v0.w) + w1 * bf2f(v1.w) + w2 * bf2f(v2.w) + w3 * bf2f(v3.w);
        }
        for (; p < end; ++p) {
            int2 e0 = e_sw[p];
            ushort4 v0 = *reinterpret_cast<const ushort4*>(x + (size_t)e0.x * F + lane * 4);
            float w0 = i2f(e0.y);
            a0 += w0 * bf2f(v0.x); a1 += w0 * bf2f(v0.y);
            a2 += w0 * bf2f(v0.z); a3 += w0 * bf2f(v0.w);
        }
        ushort4 o;
        o.x = f2bf(a0); o.y = f2bf(a1); o.z = f2bf(a2); o.w = f2bf(a3);
        *reinterpret_cast<ushort4*>(agg + (size_t)wid * F + lane * 4) = o;
    } else {  // F == 128: 2 bf16 per lane
        float a0 = 0.f, a1 = 0.f;
        for (; p + 4 <= end; p += 4) {
            int2 e0 = e_sw[p], e1 = e_sw[p + 1], e2 = e_sw[p + 2], e3 = e_sw[p + 3];
            unsigned int v0 = *reinterpret_cast<const unsigned int*>(x + (size_t)e0.x * F + lane * 2);
            unsigned int v1 = *reinterpret_cast<const unsigned int*>(x + (size_t)e1.x * F + lane * 2);
            unsigned int v2 = *reinterpret_cast<const unsigned int*>(x + (size_t)e2.x * F + lane * 2);
            unsigned int v3 = *reinterpret_cast<const unsigned int*>(x + (size_t)e3.x * F + lane * 2);
            float w0 = i2f(e0.y), w1 = i2f(e1.y), w2 = i2f(e2.y), w3 = i2f(e3.y);
            a0 += w0 * bf2f((unsigned short)v0) + w1 * bf2f((unsigned short)v1)
                + w2 * bf2f((unsigned short)v2) + w3 * bf2f((unsigned short)v3);
            a1 += w0 * bf2f((unsigned short)(v0 >> 16)) + w1 * bf2f((unsigned short)(v1 >> 16))
                + w2 * bf2f((unsigned short)(v2 >> 16)) + w3 * bf2f((unsigned short)(v3 >> 16));
        }
        for (; p < end; ++p) {
            int2 e0 = e_sw[p];
            unsigned int v0 = *reinterpret_cast<const unsigned int*>(x + (size_t)e0.x * F + lane * 2);
            float w0 = i2f(e0.y);
            a0 += w0 * bf2f((unsigned short)v0);
            a1 += w0 * bf2f((unsigned short)(v0 >> 16));
        }
        unsigned int o = (unsigned int)f2bf(a0) | ((unsigned int)f2bf(a1) << 16);
        *reinterpret_cast<unsigned int*>(agg + (size_t)wid * F + lane * 2) = o;
    }
}

// ---- final: out[node] = root[node] + sum_e w * t[src], F=64, 16 lanes/node ----
__global__ void gather_out_k(const unsigned short* __restrict__ t, const float* __restrict__ root,
                             const int* __restrict__ offsets, const int2* __restrict__ e_sw,
                             float* __restrict__ out, int Nn) {
    int gt = blockIdx.x * blockDim.x + threadIdx.x;
    int node = gt >> 4;
    int li = gt & 15;
    if (node >= Nn) return;
    int p = offsets[node], end = offsets[node + 1];
    float a0 = 0.f, a1 = 0.f, a2 = 0.f, a3 = 0.f;
    for (; p + 4 <= end; p += 4) {
        int2 e0 = e_sw[p], e1 = e_sw[p + 1], e2 = e_sw[p + 2], e3 = e_sw[p + 3];
        ushort4 v0 = *reinterpret_cast<const ushort4*>(t + (size_t)e0.x * 64 + li * 4);
        ushort4 v1 = *reinterpret_cast<const ushort4*>(t + (size_t)e1.x * 64 + li * 4);
        ushort4 v2 = *reinterpret_cast<const ushort4*>(t + (size_t)e2.x * 64 + li * 4);
        ushort4 v3 = *reinterpret_cast<const ushort4*>(t + (size_t)e3.x * 64 + li * 4);
        float w0 = i2f(e0.y), w1 = i2f(e1.y), w2 = i2f(e2.y), w3 = i2f(e3.y);
        a0 += w0 * bf2f(v0.x) + w1 * bf2f(v1.x) + w2 * bf2f(v2.x) + w3 * bf2f(v3.x);
        a1 += w0 * bf2f(v0.y) + w1 * bf2f(v1.y) + w2 * bf2f(v2.y) + w3 * bf2f(v3.y);
        a2 += w0 * bf2f(v0.z) + w1 * bf2f(v1.z) + w2 * bf2f(v2.z) + w3 * bf2f(v3.z);
        a3 += w0 * bf2f(v0.w) + w1 * bf2f(v1.w) + w2 * bf2f(v2.w) + w3 * bf2f(v3.w);
    }
    for (; p < end; ++p) {
        int2 e0 = e_sw[p];
        ushort4 v0 = *reinterpret_cast<const ushort4*>(t + (size_t)e0.x * 64 + li * 4);
        float w0 = i2f(e0.y);
        a0 += w0 * bf2f(v0.x); a1 += w0 * bf2f(v0.y);
        a2 += w0 * bf2f(v0.z); a3 += w0 * bf2f(v0.w);
    }
    float4 r = *reinterpret_cast<const float4*>(root + (size_t)node * 64 + li * 4);
    float4 o = make_float4(r.x + a0, r.y + a1, r.z + a2, r.w + a3);
    *reinterpret_cast<float4*>(out + (size_t)node * 64 + li * 4) = o;
}

// ---------------- bf16 MFMA GEMM ----------------
// MODE 0 (dual): h = A@Wa.T + X@Wb.T + bias -> bf16 out_bf[NP][O]; fused col stats.
// MODE 1 (single, O=128): cols 0-63 -> t_bf (bf16, no bias); cols 64-127 -> root f32 + bias.
// LDS: row-major [rows][64] bf16, 16B-slot XOR swizzle (slot ^= row&7) via
// pre-swizzled global source + linear global_load_lds dest (both-sides rule).
template<int K, int O, int BM, int MODE>
__global__ __launch_bounds__(256) void gemm_mfma_k(
        const unsigned short* __restrict__ A, const unsigned short* __restrict__ Wa,
        const unsigned short* __restrict__ X, const unsigned short* __restrict__ Wb,
        const float* __restrict__ bias, unsigned short* __restrict__ out_bf,
        float* __restrict__ out_f, float* __restrict__ sums, float* __restrict__ sumsq,
        int Nn) {
    constexpr int WN = 4;
    constexpr int MI = BM / 16;
    constexpr int OJ = O / (WN * 16);
    constexpr int ACH = BM / 32;
    constexpr int BCH = O / 32;
    __shared__ unsigned short As[BM * 64];
    __shared__ unsigned short Bs[O * 64];
    const int tid = threadIdx.x;
    const int w = tid >> 6, l = tid & 63;
    const int lrow = l & 15, kgrp = l >> 4;
    const int m0 = blockIdx.x * BM;

    f32x4 acc[MI][OJ];
    #pragma unroll
    for (int i = 0; i < MI; ++i)
        #pragma unroll
        for (int j = 0; j < OJ; ++j) {
            f32x4 z = {0.f, 0.f, 0.f, 0.f};
            acc[i][j] = z;
        }

    const int NPH = (MODE == 0) ? 2 : 1;
    for (int phase = 0; phase < NPH; ++phase) {
        const unsigned short* Ap = phase ? X : A;
        const unsigned short* Wp = phase ? Wb : Wa;
        for (int k0 = 0; k0 < K; k0 += 64) {
            __syncthreads();
            #pragma unroll
            for (int i = 0; i < ACH; ++i) {
                int c = i * 256 + tid;
                int row = c >> 3, slot = c & 7;
                gload_lds16(Ap + (size_t)(m0 + row) * K + k0 + ((slot ^ (row & 7)) << 3),
                            &As[(i * 256 + w * 64) * 8]);
            }
            #pragma unroll
            for (int i = 0; i < BCH; ++i) {
                int c = i * 256 + tid;
                int row = c >> 3, slot = c & 7;
                gload_lds16(Wp + (size_t)row * K + k0 + ((slot ^ (row & 7)) << 3),
                            &Bs[(i * 256 + w * 64) * 8]);
            }
            __syncthreads();
            #pragma unroll
            for (int ks = 0; ks < 2; ++ks) {
                bf16x8 a[MI], b[OJ];
                #pragma unroll
                for (int mi = 0; mi < MI; ++mi) {
                    int row = mi * 16 + lrow;
                    int slot = (ks * 4 + kgrp) ^ (row & 7);
                    a[mi] = *reinterpret_cast<const bf16x8*>(&As[row * 64 + slot * 8]);
                }
                #pragma unroll
                for (int oj = 0; oj < OJ; ++oj) {
                    int row = w * (OJ * 16) + oj * 16 + lrow;
                    int slot = (ks * 4 + kgrp) ^ (row & 7);
                    b[oj] = *reinterpret_cast<const bf16x8*>(&Bs[row * 64 + slot * 8]);
                }
                #pragma unroll
                for (int mi = 0; mi < MI; ++mi)
                    #pragma unroll
                    for (int oj = 0; oj < OJ; ++oj)
                        acc[mi][oj] = __builtin_amdgcn_mfma_f32_16x16x32_bf16(
                            a[mi], b[oj], acc[mi][oj], 0, 0, 0);
            }
        }
    }

    if constexpr (MODE == 0) {
        #pragma unroll
        for (int oj = 0; oj < OJ; ++oj) {
            int col = w * (OJ * 16) + oj * 16 + lrow;
            float bcol = bias[col];
            float s = 0.f, q = 0.f;
            #pragma unroll
            for (int mi = 0; mi < MI; ++mi) {
                #pragma unroll
                for (int r = 0; r < 4; ++r) {
                    int row = m0 + mi * 16 + kgrp * 4 + r;
                    float v = acc[mi][oj][r] + bcol;
                    if (row < Nn) {
                        out_bf[(size_t)row * O + col] = f2bf(v);
                        s += v; q += v * v;
                    }
                }
            }
            s += __shfl_xor(s, 16, 64); q += __shfl_xor(q, 16, 64);
            s += __shfl_xor(s, 32, 64); q += __shfl_xor(q, 32, 64);
            if (kgrp == 0) {
                atomicAdd(&sums[col], s);
                atomicAdd(&sumsq[col], q);
            }
        }
    } else {
        #pragma unroll
        for (int oj = 0; oj < OJ; ++oj) {
            int col = w * (OJ * 16) + oj * 16 + lrow;
            #pragma unroll
            for (int mi = 0; mi < MI; ++mi) {
                #pragma unroll
                for (int r = 0; r < 4; ++r) {
                    int row = m0 + mi * 16 + kgrp * 4 + r;
                    if (row < Nn) {
                        if (col < 64)
                            out_bf[(size_t)row * 64 + col] = f2bf(acc[mi][oj][r]);
                        else
                            out_f[(size_t)row * 64 + (col - 64)] = acc[mi][oj][r] + bias[col - 64];
                    }
                }
            }
        }
    }
}

// ---------------- BN ----------------
__global__ void bn_coef_k(const float* __restrict__ sums, const float* __restrict__ sumsq,
                          const float* __restrict__ g, const float* __restrict__ be,
                          float* __restrict__ scale, float* __restrict__ shift, float invN) {
    int f = threadIdx.x;
    float mu = sums[f] * invN;
    float var = sumsq[f] * invN - mu * mu;
    float sc = g[f] * rsqrtf(var + 1e-5f);
    scale[f] = sc;
    shift[f] = be[f] - mu * sc;
}

__global__ void bn_relu_bf_k(const unsigned short* __restrict__ h, const float* __restrict__ scale,
                             const float* __restrict__ shift, unsigned short* __restrict__ hb,
                             int total4) {
    int t = blockIdx.x * blockDim.x + threadIdx.x;
    if (t >= total4) return;
    int f0 = (t & 63) * 4;
    ushort4 v = reinterpret_cast<const ushort4*>(h)[t];
    float4 sc = *reinterpret_cast<const float4*>(scale + f0);
    float4 sh = *reinterpret_cast<const float4*>(shift + f0);
    ushort4 o;
    o.x = f2bf(fmaxf(bf2f(v.x) * sc.x + sh.x, 0.f));
    o.y = f2bf(fmaxf(bf2f(v.y) * sc.y + sh.y, 0.f));
    o.z = f2bf(fmaxf(bf2f(v.z) * sc.z + sh.z, 0.f));
    o.w = f2bf(fmaxf(bf2f(v.w) * sc.w + sh.w, 0.f));
    reinterpret_cast<ushort4*>(hb)[t] = o;
}

extern "C" void kernel_launch(void* const* d_in, const int* in_sizes, int n_in,
                              void* d_out, int out_size, void* d_ws, size_t ws_size,
                              hipStream_t stream) {
    const float* x   = (const float*)d_in[0];
    const int*   ei  = (const int*)d_in[1];
    const float* ew  = (const float*)d_in[2];
    const float* Wr0 = (const float*)d_in[3];
    const float* br0 = (const float*)d_in[4];
    const float* Wt0 = (const float*)d_in[5];
    const float* g0  = (const float*)d_in[6];
    const float* be0 = (const float*)d_in[7];
    const float* Wr1 = (const float*)d_in[8];
    const float* br1 = (const float*)d_in[9];
    const float* Wt1 = (const float*)d_in[10];
    const float* g1  = (const float*)d_in[11];
    const float* be1 = (const float*)d_in[12];
    const float* Wr2 = (const float*)d_in[13];
    const float* br2 = (const float*)d_in[14];
    const float* Wt2 = (const float*)d_in[15];

    const int E  = in_sizes[2];          // 800000
    const int Nn = in_sizes[0] / 128;    // 50000
    const size_t NP = 50176;             // padded rows (multiple of 256)
    const int* src = ei;
    const int* dst = ei + E;

    // ---- workspace layout ----
    unsigned short* x_bf   = (unsigned short*)d_ws;        // NP*128
    unsigned short* agg_bf = x_bf + NP * 128;              // NP*256
    unsigned short* h0N    = agg_bf + NP * 256;            // NP*256
    unsigned short* h1N    = h0N + NP * 256;               // NP*256
    unsigned short* h_bf   = h1N + NP * 256;               // NP*256 (raw GEMM out, reused)
    unsigned short* t_bf   = h_bf + NP * 256;              // NP*64
    unsigned short* wbf    = t_bf + NP * 64;               // 229376
    unsigned short* Wr0b = wbf;
    unsigned short* Wt0b = wbf + 32768;
    unsigned short* Wr1b = wbf + 65536;
    unsigned short* Wt1b = wbf + 131072;
    unsigned short* W2cat = wbf + 196608;                  // Wr2 (64x256) | Wt2 (64x256)
    float* root  = (float*)(wbf + 229376);                 // NP*64 f32
    float* stats = root + NP * 64;                         // 4096 f: L0 sums/sq/scale/shift, L1 same
    int2*  e_sw  = (int2*)(stats + 4096);                  // E
    int*   offsets = (int*)(e_sw + E);                     // Nn+1
    int*   counts  = offsets + Nn + 1;                     // Nn (reused as cursor)
    int*   partial = counts + Nn;                          // Nn
    int*   blocksum = partial + Nn;                        // 512

    dim3 blk(256);
    const int nbScan = (Nn + SCAN_B - 1) / SCAN_B;
    const float invN = 1.0f / (float)Nn;

    // ---- CSR build ----
    hipMemsetAsync(counts, 0, (size_t)Nn * sizeof(int), stream);
    hist_k<<<dim3((E + 255) / 256), blk, 0, stream>>>(dst, counts, E);
    scan1_k<<<dim3(nbScan), dim3(SCAN_B), 0, stream>>>(counts, partial, blocksum, Nn);
    scan2_k<<<dim3(1), dim3(256), 0, stream>>>(blocksum, nbScan);
    scan3_k<<<dim3(nbScan), dim3(SCAN_B), 0, stream>>>(partial, blocksum, offsets, Nn);
    hipMemsetAsync(counts, 0, (size_t)Nn * sizeof(int), stream);
    fill_k<<<dim3((E + 255) / 256), blk, 0, stream>>>(src, dst, ew, offsets, counts, e_sw, E);

    // ---- conversions ----
    f2bf_k<<<dim3((Nn * 32 + 255) / 256), blk, 0, stream>>>(x, x_bf, Nn * 32);
    f2bf_k<<<dim3(32), blk, 0, stream>>>(Wr0, Wr0b, 8192);
    f2bf_k<<<dim3(32), blk, 0, stream>>>(Wt0, Wt0b, 8192);
    f2bf_k<<<dim3(64), blk, 0, stream>>>(Wr1, Wr1b, 16384);
    f2bf_k<<<dim3(64), blk, 0, stream>>>(Wt1, Wt1b, 16384);
    f2bf_k<<<dim3(16), blk, 0, stream>>>(Wr2, W2cat, 4096);
    f2bf_k<<<dim3(16), blk, 0, stream>>>(Wt2, W2cat + 16384, 4096);

    hipMemsetAsync(stats, 0, 4096 * sizeof(float), stream);

    const int gatherBlocks = (Nn * 64 + 255) / 256;

    // ---------------- layer 0: K=128 -> 256 ----------------
    gather_bf_k<128><<<dim3(gatherBlocks), blk, 0, stream>>>(x_bf, offsets, e_sw, agg_bf, Nn);
    gemm_mfma_k<128, 256, 128, 0><<<dim3(NP / 128), blk, 0, stream>>>(
        agg_bf, Wr0b, x_bf, Wt0b, br0, h_bf, nullptr, stats + 0, stats + 256, Nn);
    bn_coef_k<<<dim3(1), blk, 0, stream>>>(stats + 0, stats + 256, g0, be0,
                                           stats + 512, stats + 768, invN);
    bn_relu_bf_k<<<dim3((Nn * 64 + 255) / 256), blk, 0, stream>>>(
        h_bf, stats + 512, stats + 768, h0N, Nn * 64);

    // ---------------- layer 1: K=256 -> 256 ----------------
    gather_bf_k<256><<<dim3(gatherBlocks), blk, 0, stream>>>(h0N, offsets, e_sw, agg_bf, Nn);
    gemm_mfma_k<256, 256, 128, 0><<<dim3(NP / 128), blk, 0, stream>>>(
        agg_bf, Wr1b, h0N, Wt1b, br1, h_bf, nullptr, stats + 1024, stats + 1280, Nn);
    bn_coef_k<<<dim3(1), blk, 0, stream>>>(stats + 1024, stats + 1280, g1, be1,
                                           stats + 1536, stats + 1792, invN);
    bn_relu_bf_k<<<dim3((Nn * 64 + 255) / 256), blk, 0, stream>>>(
        h_bf, stats + 1536, stats + 1792, h1N, Nn * 64);

    // ---------------- layer 2: transform-first ----------------
    // t = h1N @ Wr2.T (bf16), root = h1N @ Wt2.T + br2 (f32)
    gemm_mfma_k<256, 128, 128, 1><<<dim3(NP / 128), blk, 0, stream>>>(
        h1N, W2cat, nullptr, nullptr, br2, t_bf, root, nullptr, nullptr, Nn);
    // out = root + segment_sum(t[src] * w)
    gather_out_k<<<dim3((Nn * 16 + 255) / 256), blk, 0, stream>>>(
        t_bf, root, offsets, e_sw, (float*)d_out, Nn);
}

// Round 5
// 365.397 us; speedup vs baseline: 19.4952x; 1.0823x over previous
//
#include <hip/hip_runtime.h>
#include <cstddef>
#include <cstdint>

#define SCAN_B 512

using bf16x8 = __attribute__((ext_vector_type(8))) short;
using f32x4  = __attribute__((ext_vector_type(4))) float;

__device__ __forceinline__ unsigned short f2bf(float f) {
    unsigned int u = __builtin_bit_cast(unsigned int, f);
    return (unsigned short)((u + 0x7FFFu + ((u >> 16) & 1u)) >> 16);  // RNE
}
__device__ __forceinline__ float bf2f(unsigned short b) {
    unsigned int u = ((unsigned int)b) << 16;
    return __builtin_bit_cast(float, u);
}
__device__ __forceinline__ float i2f(int i) { return __builtin_bit_cast(float, i); }
__device__ __forceinline__ void gload_lds16(const void* g, void* l) {
    __builtin_amdgcn_global_load_lds((const __attribute__((address_space(1))) void*)g,
                                     (__attribute__((address_space(3))) void*)l, 16, 0, 0);
}

// ---------------- CSR build ----------------
__global__ void hist_k(const int* __restrict__ dst, int* __restrict__ counts, int E) {
    int e = blockIdx.x * blockDim.x + threadIdx.x;
    if (e < E) atomicAdd(&counts[dst[e]], 1);
}

__global__ void scan1_k(const int* __restrict__ counts, int* __restrict__ partial,
                        int* __restrict__ blocksum, int Nn) {
    __shared__ int sh[SCAN_B];
    int i = blockIdx.x * SCAN_B + threadIdx.x;
    int v = (i < Nn) ? counts[i] : 0;
    sh[threadIdx.x] = v;
    __syncthreads();
    for (int off = 1; off < SCAN_B; off <<= 1) {
        int t = (threadIdx.x >= (unsigned)off) ? sh[threadIdx.x - off] : 0;
        __syncthreads();
        sh[threadIdx.x] += t;
        __syncthreads();
    }
    if (i < Nn) partial[i] = sh[threadIdx.x];
    if (threadIdx.x == SCAN_B - 1) blocksum[blockIdx.x] = sh[threadIdx.x];
}

__global__ void scan2_k(int* __restrict__ blocksum, int nb) {
    __shared__ int sh[256];
    int v = (threadIdx.x < (unsigned)nb) ? blocksum[threadIdx.x] : 0;
    sh[threadIdx.x] = v;
    __syncthreads();
    for (int off = 1; off < 256; off <<= 1) {
        int t = (threadIdx.x >= (unsigned)off) ? sh[threadIdx.x - off] : 0;
        __syncthreads();
        sh[threadIdx.x] += t;
        __syncthreads();
    }
    if (threadIdx.x < (unsigned)nb) blocksum[threadIdx.x] = sh[threadIdx.x];
}

__global__ void scan3_k(const int* __restrict__ partial, const int* __restrict__ blocksum,
                        int* __restrict__ offsets, int Nn) {
    int i = blockIdx.x * SCAN_B + threadIdx.x;
    if (i >= Nn) return;
    int add = (blockIdx.x > 0) ? blocksum[blockIdx.x - 1] : 0;
    offsets[i + 1] = partial[i] + add;
    if (i == 0) offsets[0] = 0;
}

__global__ void fill_k(const int* __restrict__ src, const int* __restrict__ dst,
                       const float* __restrict__ ew, const int* __restrict__ offsets,
                       int* __restrict__ cursor, int2* __restrict__ e_sw, int E) {
    int e = blockIdx.x * blockDim.x + threadIdx.x;
    if (e >= E) return;
    int d = dst[e];
    int pos = offsets[d] + atomicAdd(&cursor[d], 1);
    e_sw[pos] = make_int2(src[e], __builtin_bit_cast(int, ew[e]));
}

// ---------------- f32 -> bf16 convert ----------------
__global__ void f2bf_k(const float* __restrict__ src, unsigned short* __restrict__ dst, int n4) {
    int i = blockIdx.x * blockDim.x + threadIdx.x;
    if (i >= n4) return;
    float4 v = reinterpret_cast<const float4*>(src)[i];
    ushort4 o;
    o.x = f2bf(v.x); o.y = f2bf(v.y); o.z = f2bf(v.z); o.w = f2bf(v.w);
    reinterpret_cast<ushort4*>(dst)[i] = o;
}

// ---------------- gather (CSR, bf16 in/out, f32 acc, 4-way pipelined) ----------------
template<int F>
__global__ void gather_bf_k(const unsigned short* __restrict__ x, const int* __restrict__ offsets,
                            const int2* __restrict__ e_sw, unsigned short* __restrict__ agg, int Nn) {
    int wid = (blockIdx.x * blockDim.x + threadIdx.x) >> 6;
    int lane = threadIdx.x & 63;
    if (wid >= Nn) return;
    int p = offsets[wid], end = offsets[wid + 1];
    if constexpr (F == 256) {
        float a0 = 0.f, a1 = 0.f, a2 = 0.f, a3 = 0.f;
        for (; p + 4 <= end; p += 4) {
            int2 e0 = e_sw[p], e1 = e_sw[p + 1], e2 = e_sw[p + 2], e3 = e_sw[p + 3];
            ushort4 v0 = *reinterpret_cast<const ushort4*>(x + (size_t)e0.x * F + lane * 4);
            ushort4 v1 = *reinterpret_cast<const ushort4*>(x + (size_t)e1.x * F + lane * 4);
            ushort4 v2 = *reinterpret_cast<const ushort4*>(x + (size_t)e2.x * F + lane * 4);
            ushort4 v3 = *reinterpret_cast<const ushort4*>(x + (size_t)e3.x * F + lane * 4);
            float w0 = i2f(e0.y), w1 = i2f(e1.y), w2 = i2f(e2.y), w3 = i2f(e3.y);
            a0 += w0 * bf2f(v0.x) + w1 * bf2f(v1.x) + w2 * bf2f(v2.x) + w3 * bf2f(v3.x);
            a1 += w0 * bf2f(v0.y) + w1 * bf2f(v1.y) + w2 * bf2f(v2.y) + w3 * bf2f(v3.y);
            a2 += w0 * bf2f(v0.z) + w1 * bf2f(v1.z) + w2 * bf2f(v2.z) + w3 * bf2f(v3.z);
            a3 += w0 * bf2f(v0.w) + w1 * bf2f(v1.w) + w2 * bf2f(v2.w) + w3 * bf2f(v3.w);
        }
        for (; p < end; ++p) {
            int2 e0 = e_sw[p];
            ushort4 v0 = *reinterpret_cast<const ushort4*>(x + (size_t)e0.x * F + lane * 4);
            float w0 = i2f(e0.y);
            a0 += w0 * bf2f(v0.x); a1 += w0 * bf2f(v0.y);
            a2 += w0 * bf2f(v0.z); a3 += w0 * bf2f(v0.w);
        }
        ushort4 o;
        o.x = f2bf(a0); o.y = f2bf(a1); o.z = f2bf(a2); o.w = f2bf(a3);
        *reinterpret_cast<ushort4*>(agg + (size_t)wid * F + lane * 4) = o;
    } else {  // F == 128: 2 bf16 per lane
        float a0 = 0.f, a1 = 0.f;
        for (; p + 4 <= end; p += 4) {
            int2 e0 = e_sw[p], e1 = e_sw[p + 1], e2 = e_sw[p + 2], e3 = e_sw[p + 3];
            unsigned int v0 = *reinterpret_cast<const unsigned int*>(x + (size_t)e0.x * F + lane * 2);
            unsigned int v1 = *reinterpret_cast<const unsigned int*>(x + (size_t)e1.x * F + lane * 2);
            unsigned int v2 = *reinterpret_cast<const unsigned int*>(x + (size_t)e2.x * F + lane * 2);
            unsigned int v3 = *reinterpret_cast<const unsigned int*>(x + (size_t)e3.x * F + lane * 2);
            float w0 = i2f(e0.y), w1 = i2f(e1.y), w2 = i2f(e2.y), w3 = i2f(e3.y);
            a0 += w0 * bf2f((unsigned short)v0) + w1 * bf2f((unsigned short)v1)
                + w2 * bf2f((unsigned short)v2) + w3 * bf2f((unsigned short)v3);
            a1 += w0 * bf2f((unsigned short)(v0 >> 16)) + w1 * bf2f((unsigned short)(v1 >> 16))
                + w2 * bf2f((unsigned short)(v2 >> 16)) + w3 * bf2f((unsigned short)(v3 >> 16));
        }
        for (; p < end; ++p) {
            int2 e0 = e_sw[p];
            unsigned int v0 = *reinterpret_cast<const unsigned int*>(x + (size_t)e0.x * F + lane * 2);
            float w0 = i2f(e0.y);
            a0 += w0 * bf2f((unsigned short)v0);
            a1 += w0 * bf2f((unsigned short)(v0 >> 16));
        }
        unsigned int o = (unsigned int)f2bf(a0) | ((unsigned int)f2bf(a1) << 16);
        *reinterpret_cast<unsigned int*>(agg + (size_t)wid * F + lane * 2) = o;
    }
}

// ---- final: out[node] = root[node] + sum_e w * t[src], F=64, 16 lanes/node ----
__global__ void gather_out_k(const unsigned short* __restrict__ t, const float* __restrict__ root,
                             const int* __restrict__ offsets, const int2* __restrict__ e_sw,
                             float* __restrict__ out, int Nn) {
    int gt = blockIdx.x * blockDim.x + threadIdx.x;
    int node = gt >> 4;
    int li = gt & 15;
    if (node >= Nn) return;
    int p = offsets[node], end = offsets[node + 1];
    float a0 = 0.f, a1 = 0.f, a2 = 0.f, a3 = 0.f;
    for (; p + 4 <= end; p += 4) {
        int2 e0 = e_sw[p], e1 = e_sw[p + 1], e2 = e_sw[p + 2], e3 = e_sw[p + 3];
        ushort4 v0 = *reinterpret_cast<const ushort4*>(t + (size_t)e0.x * 64 + li * 4);
        ushort4 v1 = *reinterpret_cast<const ushort4*>(t + (size_t)e1.x * 64 + li * 4);
        ushort4 v2 = *reinterpret_cast<const ushort4*>(t + (size_t)e2.x * 64 + li * 4);
        ushort4 v3 = *reinterpret_cast<const ushort4*>(t + (size_t)e3.x * 64 + li * 4);
        float w0 = i2f(e0.y), w1 = i2f(e1.y), w2 = i2f(e2.y), w3 = i2f(e3.y);
        a0 += w0 * bf2f(v0.x) + w1 * bf2f(v1.x) + w2 * bf2f(v2.x) + w3 * bf2f(v3.x);
        a1 += w0 * bf2f(v0.y) + w1 * bf2f(v1.y) + w2 * bf2f(v2.y) + w3 * bf2f(v3.y);
        a2 += w0 * bf2f(v0.z) + w1 * bf2f(v1.z) + w2 * bf2f(v2.z) + w3 * bf2f(v3.z);
        a3 += w0 * bf2f(v0.w) + w1 * bf2f(v1.w) + w2 * bf2f(v2.w) + w3 * bf2f(v3.w);
    }
    for (; p < end; ++p) {
        int2 e0 = e_sw[p];
        ushort4 v0 = *reinterpret_cast<const ushort4*>(t + (size_t)e0.x * 64 + li * 4);
        float w0 = i2f(e0.y);
        a0 += w0 * bf2f(v0.x); a1 += w0 * bf2f(v0.y);
        a2 += w0 * bf2f(v0.z); a3 += w0 * bf2f(v0.w);
    }
    float4 r = *reinterpret_cast<const float4*>(root + (size_t)node * 64 + li * 4);
    float4 o = make_float4(r.x + a0, r.y + a1, r.z + a2, r.w + a3);
    *reinterpret_cast<float4*>(out + (size_t)node * 64 + li * 4) = o;
}

// ---------------- bf16 MFMA GEMM, double-buffered stage-early pipeline ----------------
// MODE 0 (dual): h = A@Wa.T + X@Wb.T + bias -> bf16 out_bf[NP][O]; fused col stats.
//   grid (NP/BM, O/BN). MODE 1 (single, O=BN=128): cols 0-63 -> t_bf (bf16, no
//   bias); cols 64-127 -> root f32 + bias. grid (NP/BM, 1).
// LDS: per buffer, row-major [rows][8 slots][16B] bf16 with 16B-slot XOR swizzle
// (slot ^= row&7) via pre-swizzled global source + linear global_load_lds dest.
// Pipeline: stage(buf^1, t+1) issued BEFORE compute on buf; single
// __syncthreads per k-step (drains vmcnt+lgkmcnt). Buffer written at iter t had
// all its readers complete before the barrier ending iter t-1 -> race-free.
template<int K, int O, int BM, int BN, int MODE>
__global__ __launch_bounds__(256) void gemm_mfma_k(
        const unsigned short* __restrict__ A, const unsigned short* __restrict__ Wa,
        const unsigned short* __restrict__ X, const unsigned short* __restrict__ Wb,
        const float* __restrict__ bias, unsigned short* __restrict__ out_bf,
        float* __restrict__ out_f, float* __restrict__ sums, float* __restrict__ sumsq,
        int Nn) {
    constexpr int MI = BM / 16;                    // 8
    constexpr int OJ = BN / 64;                    // 2 (per-wave cols = BN/4)
    constexpr int KSTEPS = K / 64;
    constexpr int NT = (MODE == 0 ? 2 : 1) * KSTEPS;
    constexpr int ACH = BM / 32;
    constexpr int BCH = BN / 32;
    __shared__ unsigned short As[2][BM * 64];
    __shared__ unsigned short Bs[2][BN * 64];
    const int tid = threadIdx.x;
    const int w = tid >> 6, l = tid & 63;
    const int lrow = l & 15, kgrp = l >> 4;
    // XCD-bijective swizzle on x (gridDim.x % 8 == 0 guaranteed by launch)
    int bx = blockIdx.x;
    bx = (bx & 7) * (gridDim.x >> 3) + (bx >> 3);
    const int m0 = bx * BM;
    const int n0 = blockIdx.y * BN;

    auto stage = [&](int buf, int t) {
        int ph = t / KSTEPS;
        int k0 = (t % KSTEPS) * 64;
        const unsigned short* Ap = (MODE == 0 && ph) ? X : A;
        const unsigned short* Wp = (MODE == 0 && ph) ? Wb : Wa;
        #pragma unroll
        for (int i = 0; i < ACH; ++i) {
            int c = i * 256 + tid;
            int row = c >> 3, slot = c & 7;
            gload_lds16(Ap + (size_t)(m0 + row) * K + k0 + ((slot ^ (row & 7)) << 3),
                        &As[buf][(i * 256 + w * 64) * 8]);
        }
        #pragma unroll
        for (int i = 0; i < BCH; ++i) {
            int c = i * 256 + tid;
            int row = c >> 3, slot = c & 7;
            gload_lds16(Wp + (size_t)(n0 + row) * K + k0 + ((slot ^ (row & 7)) << 3),
                        &Bs[buf][(i * 256 + w * 64) * 8]);
        }
    };

    f32x4 acc[MI][OJ];
    #pragma unroll
    for (int i = 0; i < MI; ++i)
        #pragma unroll
        for (int j = 0; j < OJ; ++j) {
            f32x4 z = {0.f, 0.f, 0.f, 0.f};
            acc[i][j] = z;
        }

    stage(0, 0);
    __syncthreads();
    #pragma unroll
    for (int t = 0; t < NT; ++t) {
        const int cur = t & 1;
        if (t + 1 < NT) stage(cur ^ 1, t + 1);
        #pragma unroll
        for (int ks = 0; ks < 2; ++ks) {
            bf16x8 a[MI], b[OJ];
            #pragma unroll
            for (int mi = 0; mi < MI; ++mi) {
                int row = mi * 16 + lrow;
                int slot = (ks * 4 + kgrp) ^ (row & 7);
                a[mi] = *reinterpret_cast<const bf16x8*>(&As[cur][row * 64 + slot * 8]);
            }
            #pragma unroll
            for (int oj = 0; oj < OJ; ++oj) {
                int row = w * (OJ * 16) + oj * 16 + lrow;
                int slot = (ks * 4 + kgrp) ^ (row & 7);
                b[oj] = *reinterpret_cast<const bf16x8*>(&Bs[cur][row * 64 + slot * 8]);
            }
            #pragma unroll
            for (int mi = 0; mi < MI; ++mi)
                #pragma unroll
                for (int oj = 0; oj < OJ; ++oj)
                    acc[mi][oj] = __builtin_amdgcn_mfma_f32_16x16x32_bf16(
                        a[mi], b[oj], acc[mi][oj], 0, 0, 0);
        }
        __syncthreads();   // drains vmcnt (next-tile stage) + lgkmcnt (this tile's reads)
    }

    if constexpr (MODE == 0) {
        #pragma unroll
        for (int oj = 0; oj < OJ; ++oj) {
            int col = n0 + w * (OJ * 16) + oj * 16 + lrow;
            float bcol = bias[col];
            float s = 0.f, q = 0.f;
            #pragma unroll
            for (int mi = 0; mi < MI; ++mi) {
                #pragma unroll
                for (int r = 0; r < 4; ++r) {
                    int row = m0 + mi * 16 + kgrp * 4 + r;
                    float v = acc[mi][oj][r] + bcol;
                    if (row < Nn) {
                        out_bf[(size_t)row * O + col] = f2bf(v);
                        s += v; q += v * v;
                    }
                }
            }
            s += __shfl_xor(s, 16, 64); q += __shfl_xor(q, 16, 64);
            s += __shfl_xor(s, 32, 64); q += __shfl_xor(q, 32, 64);
            if (kgrp == 0) {
                atomicAdd(&sums[col], s);
                atomicAdd(&sumsq[col], q);
            }
        }
    } else {
        #pragma unroll
        for (int oj = 0; oj < OJ; ++oj) {
            int col = n0 + w * (OJ * 16) + oj * 16 + lrow;
            #pragma unroll
            for (int mi = 0; mi < MI; ++mi) {
                #pragma unroll
                for (int r = 0; r < 4; ++r) {
                    int row = m0 + mi * 16 + kgrp * 4 + r;
                    if (row < Nn) {
                        if (col < 64)
                            out_bf[(size_t)row * 64 + col] = f2bf(acc[mi][oj][r]);
                        else
                            out_f[(size_t)row * 64 + (col - 64)] = acc[mi][oj][r] + bias[col - 64];
                    }
                }
            }
        }
    }
}

// ---------------- BN ----------------
__global__ void bn_coef_k(const float* __restrict__ sums, const float* __restrict__ sumsq,
                          const float* __restrict__ g, const float* __restrict__ be,
                          float* __restrict__ scale, float* __restrict__ shift, float invN) {
    int f = threadIdx.x;
    float mu = sums[f] * invN;
    float var = sumsq[f] * invN - mu * mu;
    float sc = g[f] * rsqrtf(var + 1e-5f);
    scale[f] = sc;
    shift[f] = be[f] - mu * sc;
}

__global__ void bn_relu_bf_k(const unsigned short* __restrict__ h, const float* __restrict__ scale,
                             const float* __restrict__ shift, unsigned short* __restrict__ hb,
                             int total4) {
    int t = blockIdx.x * blockDim.x + threadIdx.x;
    if (t >= total4) return;
    int f0 = (t & 63) * 4;
    ushort4 v = reinterpret_cast<const ushort4*>(h)[t];
    float4 sc = *reinterpret_cast<const float4*>(scale + f0);
    float4 sh = *reinterpret_cast<const float4*>(shift + f0);
    ushort4 o;
    o.x = f2bf(fmaxf(bf2f(v.x) * sc.x + sh.x, 0.f));
    o.y = f2bf(fmaxf(bf2f(v.y) * sc.y + sh.y, 0.f));
    o.z = f2bf(fmaxf(bf2f(v.z) * sc.z + sh.z, 0.f));
    o.w = f2bf(fmaxf(bf2f(v.w) * sc.w + sh.w, 0.f));
    reinterpret_cast<ushort4*>(hb)[t] = o;
}

extern "C" void kernel_launch(void* const* d_in, const int* in_sizes, int n_in,
                              void* d_out, int out_size, void* d_ws, size_t ws_size,
                              hipStream_t stream) {
    const float* x   = (const float*)d_in[0];
    const int*   ei  = (const int*)d_in[1];
    const float* ew  = (const float*)d_in[2];
    const float* Wr0 = (const float*)d_in[3];
    const float* br0 = (const float*)d_in[4];
    const float* Wt0 = (const float*)d_in[5];
    const float* g0  = (const float*)d_in[6];
    const float* be0 = (const float*)d_in[7];
    const float* Wr1 = (const float*)d_in[8];
    const float* br1 = (const float*)d_in[9];
    const float* Wt1 = (const float*)d_in[10];
    const float* g1  = (const float*)d_in[11];
    const float* be1 = (const float*)d_in[12];
    const float* Wr2 = (const float*)d_in[13];
    const float* br2 = (const float*)d_in[14];
    const float* Wt2 = (const float*)d_in[15];

    const int E  = in_sizes[2];          // 800000
    const int Nn = in_sizes[0] / 128;    // 50000
    const size_t NP = 50176;             // padded rows (multiple of 1024 for grid%8)
    const int* src = ei;
    const int* dst = ei + E;

    // ---- workspace layout ----
    unsigned short* x_bf   = (unsigned short*)d_ws;        // NP*128
    unsigned short* agg_bf = x_bf + NP * 128;              // NP*256
    unsigned short* h0N    = agg_bf + NP * 256;            // NP*256
    unsigned short* h1N    = h0N + NP * 256;               // NP*256
    unsigned short* h_bf   = h1N + NP * 256;               // NP*256 (raw GEMM out, reused)
    unsigned short* t_bf   = h_bf + NP * 256;              // NP*64
    unsigned short* wbf    = t_bf + NP * 64;               // 229376
    unsigned short* Wr0b = wbf;
    unsigned short* Wt0b = wbf + 32768;
    unsigned short* Wr1b = wbf + 65536;
    unsigned short* Wt1b = wbf + 131072;
    unsigned short* W2cat = wbf + 196608;                  // Wr2 (64x256) | Wt2 (64x256)
    float* root  = (float*)(wbf + 229376);                 // NP*64 f32
    float* stats = root + NP * 64;                         // 4096 f
    int2*  e_sw  = (int2*)(stats + 4096);                  // E
    int*   offsets = (int*)(e_sw + E);                     // Nn+1
    int*   counts  = offsets + Nn + 1;                     // Nn (reused as cursor)
    int*   partial = counts + Nn;                          // Nn
    int*   blocksum = partial + Nn;                        // 512

    dim3 blk(256);
    const int nbScan = (Nn + SCAN_B - 1) / SCAN_B;
    const float invN = 1.0f / (float)Nn;

    // ---- CSR build ----
    hipMemsetAsync(counts, 0, (size_t)Nn * sizeof(int), stream);
    hist_k<<<dim3((E + 255) / 256), blk, 0, stream>>>(dst, counts, E);
    scan1_k<<<dim3(nbScan), dim3(SCAN_B), 0, stream>>>(counts, partial, blocksum, Nn);
    scan2_k<<<dim3(1), dim3(256), 0, stream>>>(blocksum, nbScan);
    scan3_k<<<dim3(nbScan), dim3(SCAN_B), 0, stream>>>(partial, blocksum, offsets, Nn);
    hipMemsetAsync(counts, 0, (size_t)Nn * sizeof(int), stream);
    fill_k<<<dim3((E + 255) / 256), blk, 0, stream>>>(src, dst, ew, offsets, counts, e_sw, E);

    // ---- conversions ----
    f2bf_k<<<dim3((Nn * 32 + 255) / 256), blk, 0, stream>>>(x, x_bf, Nn * 32);
    f2bf_k<<<dim3(32), blk, 0, stream>>>(Wr0, Wr0b, 8192);
    f2bf_k<<<dim3(32), blk, 0, stream>>>(Wt0, Wt0b, 8192);
    f2bf_k<<<dim3(64), blk, 0, stream>>>(Wr1, Wr1b, 16384);
    f2bf_k<<<dim3(64), blk, 0, stream>>>(Wt1, Wt1b, 16384);
    f2bf_k<<<dim3(16), blk, 0, stream>>>(Wr2, W2cat, 4096);
    f2bf_k<<<dim3(16), blk, 0, stream>>>(Wt2, W2cat + 16384, 4096);

    hipMemsetAsync(stats, 0, 4096 * sizeof(float), stream);

    const int gatherBlocks = (Nn * 64 + 255) / 256;

    // ---------------- layer 0: K=128 -> 256 ----------------
    gather_bf_k<128><<<dim3(gatherBlocks), blk, 0, stream>>>(x_bf, offsets, e_sw, agg_bf, Nn);
    gemm_mfma_k<128, 256, 128, 128, 0><<<dim3(NP / 128, 2), blk, 0, stream>>>(
        agg_bf, Wr0b, x_bf, Wt0b, br0, h_bf, nullptr, stats + 0, stats + 256, Nn);
    bn_coef_k<<<dim3(1), blk, 0, stream>>>(stats + 0, stats + 256, g0, be0,
                                           stats + 512, stats + 768, invN);
    bn_relu_bf_k<<<dim3((Nn * 64 + 255) / 256), blk, 0, stream>>>(
        h_bf, stats + 512, stats + 768, h0N, Nn * 64);

    // ---------------- layer 1: K=256 -> 256 ----------------
    gather_bf_k<256><<<dim3(gatherBlocks), blk, 0, stream>>>(h0N, offsets, e_sw, agg_bf, Nn);
    gemm_mfma_k<256, 256, 128, 128, 0><<<dim3(NP / 128, 2), blk, 0, stream>>>(
        agg_bf, Wr1b, h0N, Wt1b, br1, h_bf, nullptr, stats + 1024, stats + 1280, Nn);
    bn_coef_k<<<dim3(1), blk, 0, stream>>>(stats + 1024, stats + 1280, g1, be1,
                                           stats + 1536, stats + 1792, invN);
    bn_relu_bf_k<<<dim3((Nn * 64 + 255) / 256), blk, 0, stream>>>(
        h_bf, stats + 1536, stats + 1792, h1N, Nn * 64);

    // ---------------- layer 2: transform-first ----------------
    // t = h1N @ Wr2.T (bf16), root = h1N @ Wt2.T + br2 (f32)
    gemm_mfma_k<256, 128, 128, 128, 1><<<dim3(NP / 128, 1), blk, 0, stream>>>(
        h1N, W2cat, nullptr, nullptr, br2, t_bf, root, nullptr, nullptr, Nn);
    // out = root + segment_sum(t[src] * w)
    gather_out_k<<<dim3((Nn * 16 + 255) / 256), blk, 0, stream>>>(
        t_bf, root, offsets, e_sw, (float*)d_out, Nn);
}

// Round 6
// 313.875 us; speedup vs baseline: 22.6953x; 1.1641x over previous
//
#include <hip/hip_runtime.h>
#include <cstddef>
#include <cstdint>

#define SCAN_B 512

using bf16x8 = __attribute__((ext_vector_type(8))) short;
using f32x4  = __attribute__((ext_vector_type(4))) float;

__device__ __forceinline__ unsigned short f2bf(float f) {
    unsigned int u = __builtin_bit_cast(unsigned int, f);
    return (unsigned short)((u + 0x7FFFu + ((u >> 16) & 1u)) >> 16);  // RNE
}
__device__ __forceinline__ float bf2f(unsigned short b) {
    unsigned int u = ((unsigned int)b) << 16;
    return __builtin_bit_cast(float, u);
}
__device__ __forceinline__ float i2f(int i) { return __builtin_bit_cast(float, i); }
__device__ __forceinline__ void gload_lds16(const void* g, void* l) {
    __builtin_amdgcn_global_load_lds((const __attribute__((address_space(1))) void*)g,
                                     (__attribute__((address_space(3))) void*)l, 16, 0, 0);
}

// ---------------- CSR build ----------------
// rank[e] = arrival order of edge e within its dst bucket (atomic, coalesced write)
__global__ void hist_rank_k(const int* __restrict__ dst, int* __restrict__ counts,
                            int* __restrict__ rank, int E) {
    int e = blockIdx.x * blockDim.x + threadIdx.x;
    if (e >= E) return;
    rank[e] = atomicAdd(&counts[dst[e]], 1);
}

__global__ void scan1_k(const int* __restrict__ counts, int* __restrict__ partial,
                        int* __restrict__ blocksum, int Nn) {
    __shared__ int sh[SCAN_B];
    int i = blockIdx.x * SCAN_B + threadIdx.x;
    int v = (i < Nn) ? counts[i] : 0;
    sh[threadIdx.x] = v;
    __syncthreads();
    for (int off = 1; off < SCAN_B; off <<= 1) {
        int t = (threadIdx.x >= (unsigned)off) ? sh[threadIdx.x - off] : 0;
        __syncthreads();
        sh[threadIdx.x] += t;
        __syncthreads();
    }
    if (i < Nn) partial[i] = sh[threadIdx.x];
    if (threadIdx.x == SCAN_B - 1) blocksum[blockIdx.x] = sh[threadIdx.x];
}

__global__ void scan2_k(int* __restrict__ blocksum, int nb) {
    __shared__ int sh[256];
    int v = (threadIdx.x < (unsigned)nb) ? blocksum[threadIdx.x] : 0;
    sh[threadIdx.x] = v;
    __syncthreads();
    for (int off = 1; off < 256; off <<= 1) {
        int t = (threadIdx.x >= (unsigned)off) ? sh[threadIdx.x - off] : 0;
        __syncthreads();
        sh[threadIdx.x] += t;
        __syncthreads();
    }
    if (threadIdx.x < (unsigned)nb) blocksum[threadIdx.x] = sh[threadIdx.x];
}

__global__ void scan3_k(const int* __restrict__ partial, const int* __restrict__ blocksum,
                        int* __restrict__ offsets, int Nn) {
    int i = blockIdx.x * SCAN_B + threadIdx.x;
    if (i >= Nn) return;
    int add = (blockIdx.x > 0) ? blocksum[blockIdx.x - 1] : 0;
    offsets[i + 1] = partial[i] + add;
    if (i == 0) offsets[0] = 0;
}

// atomic-free scatter: pos fully determined by offsets + precomputed rank
__global__ void fill2_k(const int* __restrict__ src, const int* __restrict__ dst,
                        const float* __restrict__ ew, const int* __restrict__ offsets,
                        const int* __restrict__ rank, int2* __restrict__ e_sw, int E) {
    int e = blockIdx.x * blockDim.x + threadIdx.x;
    if (e >= E) return;
    int d = dst[e];
    int pos = offsets[d] + rank[e];
    e_sw[pos] = make_int2(src[e], __builtin_bit_cast(int, ew[e]));
}

// ---------------- all f32 -> bf16 conversions, one launch ----------------
__global__ void f2bf_all_k(const float* __restrict__ x, const float* __restrict__ Wr0,
                           const float* __restrict__ Wt0, const float* __restrict__ Wr1,
                           const float* __restrict__ Wt1, const float* __restrict__ Wr2,
                           const float* __restrict__ Wt2, unsigned short* __restrict__ x_bf,
                           unsigned short* __restrict__ Wr0b, unsigned short* __restrict__ Wt0b,
                           unsigned short* __restrict__ Wr1b, unsigned short* __restrict__ Wt1b,
                           unsigned short* __restrict__ Wr2b, unsigned short* __restrict__ Wt2b,
                           int n4x) {
    int j = blockIdx.x * blockDim.x + threadIdx.x;   // float4 index
    const float* s;
    unsigned short* d;
    if (j < n4x) { s = x; d = x_bf; }
    else {
        j -= n4x;
        if (j < 8192) { s = Wr0; d = Wr0b; }
        else { j -= 8192;
        if (j < 8192) { s = Wt0; d = Wt0b; }
        else { j -= 8192;
        if (j < 16384) { s = Wr1; d = Wr1b; }
        else { j -= 16384;
        if (j < 16384) { s = Wt1; d = Wt1b; }
        else { j -= 16384;
        if (j < 4096) { s = Wr2; d = Wr2b; }
        else { j -= 4096;
        if (j >= 4096) return;
        s = Wt2; d = Wt2b; } } } } }
    }
    float4 v = reinterpret_cast<const float4*>(s)[j];
    ushort4 o;
    o.x = f2bf(v.x); o.y = f2bf(v.y); o.z = f2bf(v.z); o.w = f2bf(v.w);
    reinterpret_cast<ushort4*>(d)[j] = o;
}

// ---------------- gather (CSR, bf16 in/out, f32 acc, 8-way pipelined) ----------------
template<int F>
__global__ void gather_bf_k(const unsigned short* __restrict__ x, const int* __restrict__ offsets,
                            const int2* __restrict__ e_sw, unsigned short* __restrict__ agg, int Nn) {
    int wid = (blockIdx.x * blockDim.x + threadIdx.x) >> 6;
    int lane = threadIdx.x & 63;
    if (wid >= Nn) return;
    int p = offsets[wid], end = offsets[wid + 1];
    if constexpr (F == 256) {
        float a0 = 0.f, a1 = 0.f, a2 = 0.f, a3 = 0.f;
        for (; p + 8 <= end; p += 8) {
            int2 ee[8];
            #pragma unroll
            for (int i = 0; i < 8; ++i) ee[i] = e_sw[p + i];
            ushort4 vv[8];
            #pragma unroll
            for (int i = 0; i < 8; ++i)
                vv[i] = *reinterpret_cast<const ushort4*>(x + (size_t)ee[i].x * F + lane * 4);
            #pragma unroll
            for (int i = 0; i < 8; ++i) {
                float w = i2f(ee[i].y);
                a0 += w * bf2f(vv[i].x); a1 += w * bf2f(vv[i].y);
                a2 += w * bf2f(vv[i].z); a3 += w * bf2f(vv[i].w);
            }
        }
        for (; p + 4 <= end; p += 4) {
            int2 ee[4];
            #pragma unroll
            for (int i = 0; i < 4; ++i) ee[i] = e_sw[p + i];
            ushort4 vv[4];
            #pragma unroll
            for (int i = 0; i < 4; ++i)
                vv[i] = *reinterpret_cast<const ushort4*>(x + (size_t)ee[i].x * F + lane * 4);
            #pragma unroll
            for (int i = 0; i < 4; ++i) {
                float w = i2f(ee[i].y);
                a0 += w * bf2f(vv[i].x); a1 += w * bf2f(vv[i].y);
                a2 += w * bf2f(vv[i].z); a3 += w * bf2f(vv[i].w);
            }
        }
        for (; p < end; ++p) {
            int2 e0 = e_sw[p];
            ushort4 v0 = *reinterpret_cast<const ushort4*>(x + (size_t)e0.x * F + lane * 4);
            float w0 = i2f(e0.y);
            a0 += w0 * bf2f(v0.x); a1 += w0 * bf2f(v0.y);
            a2 += w0 * bf2f(v0.z); a3 += w0 * bf2f(v0.w);
        }
        ushort4 o;
        o.x = f2bf(a0); o.y = f2bf(a1); o.z = f2bf(a2); o.w = f2bf(a3);
        *reinterpret_cast<ushort4*>(agg + (size_t)wid * F + lane * 4) = o;
    } else {  // F == 128: 2 bf16 per lane
        float a0 = 0.f, a1 = 0.f;
        for (; p + 8 <= end; p += 8) {
            int2 ee[8];
            #pragma unroll
            for (int i = 0; i < 8; ++i) ee[i] = e_sw[p + i];
            unsigned int vv[8];
            #pragma unroll
            for (int i = 0; i < 8; ++i)
                vv[i] = *reinterpret_cast<const unsigned int*>(x + (size_t)ee[i].x * F + lane * 2);
            #pragma unroll
            for (int i = 0; i < 8; ++i) {
                float w = i2f(ee[i].y);
                a0 += w * bf2f((unsigned short)vv[i]);
                a1 += w * bf2f((unsigned short)(vv[i] >> 16));
            }
        }
        for (; p < end; ++p) {
            int2 e0 = e_sw[p];
            unsigned int v0 = *reinterpret_cast<const unsigned int*>(x + (size_t)e0.x * F + lane * 2);
            float w0 = i2f(e0.y);
            a0 += w0 * bf2f((unsigned short)v0);
            a1 += w0 * bf2f((unsigned short)(v0 >> 16));
        }
        unsigned int o = (unsigned int)f2bf(a0) | ((unsigned int)f2bf(a1) << 16);
        *reinterpret_cast<unsigned int*>(agg + (size_t)wid * F + lane * 2) = o;
    }
}

// ---- final: out[node] = root[node] + sum_e w * t[src], F=64, 16 lanes/node ----
__global__ void gather_out_k(const unsigned short* __restrict__ t, const float* __restrict__ root,
                             const int* __restrict__ offsets, const int2* __restrict__ e_sw,
                             float* __restrict__ out, int Nn) {
    int gt = blockIdx.x * blockDim.x + threadIdx.x;
    int node = gt >> 4;
    int li = gt & 15;
    if (node >= Nn) return;
    int p = offsets[node], end = offsets[node + 1];
    float a0 = 0.f, a1 = 0.f, a2 = 0.f, a3 = 0.f;
    for (; p + 8 <= end; p += 8) {
        int2 ee[8];
        #pragma unroll
        for (int i = 0; i < 8; ++i) ee[i] = e_sw[p + i];
        ushort4 vv[8];
        #pragma unroll
        for (int i = 0; i < 8; ++i)
            vv[i] = *reinterpret_cast<const ushort4*>(t + (size_t)ee[i].x * 64 + li * 4);
        #pragma unroll
        for (int i = 0; i < 8; ++i) {
            float w = i2f(ee[i].y);
            a0 += w * bf2f(vv[i].x); a1 += w * bf2f(vv[i].y);
            a2 += w * bf2f(vv[i].z); a3 += w * bf2f(vv[i].w);
        }
    }
    for (; p < end; ++p) {
        int2 e0 = e_sw[p];
        ushort4 v0 = *reinterpret_cast<const ushort4*>(t + (size_t)e0.x * 64 + li * 4);
        float w0 = i2f(e0.y);
        a0 += w0 * bf2f(v0.x); a1 += w0 * bf2f(v0.y);
        a2 += w0 * bf2f(v0.z); a3 += w0 * bf2f(v0.w);
    }
    float4 r = *reinterpret_cast<const float4*>(root + (size_t)node * 64 + li * 4);
    float4 o = make_float4(r.x + a0, r.y + a1, r.z + a2, r.w + a3);
    *reinterpret_cast<float4*>(out + (size_t)node * 64 + li * 4) = o;
}

// ---------------- bf16 MFMA GEMM, double-buffered stage-early pipeline ----------------
// (unchanged from round 4 — see its header comment)
template<int K, int O, int BM, int BN, int MODE>
__global__ __launch_bounds__(256) void gemm_mfma_k(
        const unsigned short* __restrict__ A, const unsigned short* __restrict__ Wa,
        const unsigned short* __restrict__ X, const unsigned short* __restrict__ Wb,
        const float* __restrict__ bias, unsigned short* __restrict__ out_bf,
        float* __restrict__ out_f, float* __restrict__ sums, float* __restrict__ sumsq,
        int Nn) {
    constexpr int MI = BM / 16;
    constexpr int OJ = BN / 64;
    constexpr int KSTEPS = K / 64;
    constexpr int NT = (MODE == 0 ? 2 : 1) * KSTEPS;
    constexpr int ACH = BM / 32;
    constexpr int BCH = BN / 32;
    __shared__ unsigned short As[2][BM * 64];
    __shared__ unsigned short Bs[2][BN * 64];
    const int tid = threadIdx.x;
    const int w = tid >> 6, l = tid & 63;
    const int lrow = l & 15, kgrp = l >> 4;
    int bx = blockIdx.x;
    bx = (bx & 7) * (gridDim.x >> 3) + (bx >> 3);
    const int m0 = bx * BM;
    const int n0 = blockIdx.y * BN;

    auto stage = [&](int buf, int t) {
        int ph = t / KSTEPS;
        int k0 = (t % KSTEPS) * 64;
        const unsigned short* Ap = (MODE == 0 && ph) ? X : A;
        const unsigned short* Wp = (MODE == 0 && ph) ? Wb : Wa;
        #pragma unroll
        for (int i = 0; i < ACH; ++i) {
            int c = i * 256 + tid;
            int row = c >> 3, slot = c & 7;
            gload_lds16(Ap + (size_t)(m0 + row) * K + k0 + ((slot ^ (row & 7)) << 3),
                        &As[buf][(i * 256 + w * 64) * 8]);
        }
        #pragma unroll
        for (int i = 0; i < BCH; ++i) {
            int c = i * 256 + tid;
            int row = c >> 3, slot = c & 7;
            gload_lds16(Wp + (size_t)(n0 + row) * K + k0 + ((slot ^ (row & 7)) << 3),
                        &Bs[buf][(i * 256 + w * 64) * 8]);
        }
    };

    f32x4 acc[MI][OJ];
    #pragma unroll
    for (int i = 0; i < MI; ++i)
        #pragma unroll
        for (int j = 0; j < OJ; ++j) {
            f32x4 z = {0.f, 0.f, 0.f, 0.f};
            acc[i][j] = z;
        }

    stage(0, 0);
    __syncthreads();
    #pragma unroll
    for (int t = 0; t < NT; ++t) {
        const int cur = t & 1;
        if (t + 1 < NT) stage(cur ^ 1, t + 1);
        #pragma unroll
        for (int ks = 0; ks < 2; ++ks) {
            bf16x8 a[MI], b[OJ];
            #pragma unroll
            for (int mi = 0; mi < MI; ++mi) {
                int row = mi * 16 + lrow;
                int slot = (ks * 4 + kgrp) ^ (row & 7);
                a[mi] = *reinterpret_cast<const bf16x8*>(&As[cur][row * 64 + slot * 8]);
            }
            #pragma unroll
            for (int oj = 0; oj < OJ; ++oj) {
                int row = w * (OJ * 16) + oj * 16 + lrow;
                int slot = (ks * 4 + kgrp) ^ (row & 7);
                b[oj] = *reinterpret_cast<const bf16x8*>(&Bs[cur][row * 64 + slot * 8]);
            }
            #pragma unroll
            for (int mi = 0; mi < MI; ++mi)
                #pragma unroll
                for (int oj = 0; oj < OJ; ++oj)
                    acc[mi][oj] = __builtin_amdgcn_mfma_f32_16x16x32_bf16(
                        a[mi], b[oj], acc[mi][oj], 0, 0, 0);
        }
        __syncthreads();
    }

    if constexpr (MODE == 0) {
        #pragma unroll
        for (int oj = 0; oj < OJ; ++oj) {
            int col = n0 + w * (OJ * 16) + oj * 16 + lrow;
            float bcol = bias[col];
            float s = 0.f, q = 0.f;
            #pragma unroll
            for (int mi = 0; mi < MI; ++mi) {
                #pragma unroll
                for (int r = 0; r < 4; ++r) {
                    int row = m0 + mi * 16 + kgrp * 4 + r;
                    float v = acc[mi][oj][r] + bcol;
                    if (row < Nn) {
                        out_bf[(size_t)row * O + col] = f2bf(v);
                        s += v; q += v * v;
                    }
                }
            }
            s += __shfl_xor(s, 16, 64); q += __shfl_xor(q, 16, 64);
            s += __shfl_xor(s, 32, 64); q += __shfl_xor(q, 32, 64);
            if (kgrp == 0) {
                atomicAdd(&sums[col], s);
                atomicAdd(&sumsq[col], q);
            }
        }
    } else {
        #pragma unroll
        for (int oj = 0; oj < OJ; ++oj) {
            int col = n0 + w * (OJ * 16) + oj * 16 + lrow;
            #pragma unroll
            for (int mi = 0; mi < MI; ++mi) {
                #pragma unroll
                for (int r = 0; r < 4; ++r) {
                    int row = m0 + mi * 16 + kgrp * 4 + r;
                    if (row < Nn) {
                        if (col < 64)
                            out_bf[(size_t)row * 64 + col] = f2bf(acc[mi][oj][r]);
                        else
                            out_f[(size_t)row * 64 + (col - 64)] = acc[mi][oj][r] + bias[col - 64];
                    }
                }
            }
        }
    }
}

// ---------------- BN ----------------
__global__ void bn_coef_k(const float* __restrict__ sums, const float* __restrict__ sumsq,
                          const float* __restrict__ g, const float* __restrict__ be,
                          float* __restrict__ scale, float* __restrict__ shift, float invN) {
    int f = threadIdx.x;
    float mu = sums[f] * invN;
    float var = sumsq[f] * invN - mu * mu;
    float sc = g[f] * rsqrtf(var + 1e-5f);
    scale[f] = sc;
    shift[f] = be[f] - mu * sc;
}

__global__ void bn_relu_bf_k(const unsigned short* __restrict__ h, const float* __restrict__ scale,
                             const float* __restrict__ shift, unsigned short* __restrict__ hb,
                             int total4) {
    int t = blockIdx.x * blockDim.x + threadIdx.x;
    if (t >= total4) return;
    int f0 = (t & 63) * 4;
    ushort4 v = reinterpret_cast<const ushort4*>(h)[t];
    float4 sc = *reinterpret_cast<const float4*>(scale + f0);
    float4 sh = *reinterpret_cast<const float4*>(shift + f0);
    ushort4 o;
    o.x = f2bf(fmaxf(bf2f(v.x) * sc.x + sh.x, 0.f));
    o.y = f2bf(fmaxf(bf2f(v.y) * sc.y + sh.y, 0.f));
    o.z = f2bf(fmaxf(bf2f(v.z) * sc.z + sh.z, 0.f));
    o.w = f2bf(fmaxf(bf2f(v.w) * sc.w + sh.w, 0.f));
    reinterpret_cast<ushort4*>(hb)[t] = o;
}

extern "C" void kernel_launch(void* const* d_in, const int* in_sizes, int n_in,
                              void* d_out, int out_size, void* d_ws, size_t ws_size,
                              hipStream_t stream) {
    const float* x   = (const float*)d_in[0];
    const int*   ei  = (const int*)d_in[1];
    const float* ew  = (const float*)d_in[2];
    const float* Wr0 = (const float*)d_in[3];
    const float* br0 = (const float*)d_in[4];
    const float* Wt0 = (const float*)d_in[5];
    const float* g0  = (const float*)d_in[6];
    const float* be0 = (const float*)d_in[7];
    const float* Wr1 = (const float*)d_in[8];
    const float* br1 = (const float*)d_in[9];
    const float* Wt1 = (const float*)d_in[10];
    const float* g1  = (const float*)d_in[11];
    const float* be1 = (const float*)d_in[12];
    const float* Wr2 = (const float*)d_in[13];
    const float* br2 = (const float*)d_in[14];
    const float* Wt2 = (const float*)d_in[15];

    const int E  = in_sizes[2];          // 800000
    const int Nn = in_sizes[0] / 128;    // 50000
    const size_t NP = 50176;             // padded rows
    const int* src = ei;
    const int* dst = ei + E;

    // ---- workspace layout ----
    unsigned short* x_bf   = (unsigned short*)d_ws;        // NP*128
    unsigned short* agg_bf = x_bf + NP * 128;              // NP*256
    unsigned short* h0N    = agg_bf + NP * 256;            // NP*256
    unsigned short* h1N    = h0N + NP * 256;               // NP*256
    unsigned short* h_bf   = h1N + NP * 256;               // NP*256
    unsigned short* t_bf   = h_bf + NP * 256;              // NP*64
    unsigned short* wbf    = t_bf + NP * 64;               // 229376
    unsigned short* Wr0b = wbf;
    unsigned short* Wt0b = wbf + 32768;
    unsigned short* Wr1b = wbf + 65536;
    unsigned short* Wt1b = wbf + 131072;
    unsigned short* W2cat = wbf + 196608;                  // Wr2 | Wt2
    float* root  = (float*)(wbf + 229376);                 // NP*64 f32
    int2*  e_sw  = (int2*)(root + NP * 64);                // E (8B aligned here)
    float* stats = (float*)(e_sw + E);                     // 4096 f
    int*   counts  = (int*)(stats + 4096);                 // Nn  (memset with stats)
    int*   partial = counts + Nn;                          // Nn
    int*   blocksum = partial + Nn;                        // 512
    int*   rank    = blocksum + 512;                       // E
    int*   offsets = rank + E;                             // Nn+1

    dim3 blk(256);
    const int nbScan = (Nn + SCAN_B - 1) / SCAN_B;
    const float invN = 1.0f / (float)Nn;
    const int n4x = Nn * 32;             // x float4 count

    // ---- single memset: stats (4096 f) + counts (Nn i) ----
    hipMemsetAsync(stats, 0, (4096 + (size_t)Nn) * sizeof(float), stream);

    // ---- CSR build (rank-split: atomic in hist, atomic-free fill) ----
    hist_rank_k<<<dim3((E + 255) / 256), blk, 0, stream>>>(dst, counts, rank, E);
    scan1_k<<<dim3(nbScan), dim3(SCAN_B), 0, stream>>>(counts, partial, blocksum, Nn);
    scan2_k<<<dim3(1), dim3(256), 0, stream>>>(blocksum, nbScan);
    scan3_k<<<dim3(nbScan), dim3(SCAN_B), 0, stream>>>(partial, blocksum, offsets, Nn);
    fill2_k<<<dim3((E + 255) / 256), blk, 0, stream>>>(src, dst, ew, offsets, rank, e_sw, E);

    // ---- all conversions in one launch ----
    f2bf_all_k<<<dim3((n4x + 57344 + 255) / 256), blk, 0, stream>>>(
        x, Wr0, Wt0, Wr1, Wt1, Wr2, Wt2,
        x_bf, Wr0b, Wt0b, Wr1b, Wt1b, W2cat, W2cat + 16384, n4x);

    const int gatherBlocks = (Nn * 64 + 255) / 256;

    // ---------------- layer 0: K=128 -> 256 ----------------
    gather_bf_k<128><<<dim3(gatherBlocks), blk, 0, stream>>>(x_bf, offsets, e_sw, agg_bf, Nn);
    gemm_mfma_k<128, 256, 128, 128, 0><<<dim3(NP / 128, 2), blk, 0, stream>>>(
        agg_bf, Wr0b, x_bf, Wt0b, br0, h_bf, nullptr, stats + 0, stats + 256, Nn);
    bn_coef_k<<<dim3(1), blk, 0, stream>>>(stats + 0, stats + 256, g0, be0,
                                           stats + 512, stats + 768, invN);
    bn_relu_bf_k<<<dim3((Nn * 64 + 255) / 256), blk, 0, stream>>>(
        h_bf, stats + 512, stats + 768, h0N, Nn * 64);

    // ---------------- layer 1: K=256 -> 256 ----------------
    gather_bf_k<256><<<dim3(gatherBlocks), blk, 0, stream>>>(h0N, offsets, e_sw, agg_bf, Nn);
    gemm_mfma_k<256, 256, 128, 128, 0><<<dim3(NP / 128, 2), blk, 0, stream>>>(
        agg_bf, Wr1b, h0N, Wt1b, br1, h_bf, nullptr, stats + 1024, stats + 1280, Nn);
    bn_coef_k<<<dim3(1), blk, 0, stream>>>(stats + 1024, stats + 1280, g1, be1,
                                           stats + 1536, stats + 1792, invN);
    bn_relu_bf_k<<<dim3((Nn * 64 + 255) / 256), blk, 0, stream>>>(
        h_bf, stats + 1536, stats + 1792, h1N, Nn * 64);

    // ---------------- layer 2: transform-first ----------------
    gemm_mfma_k<256, 128, 128, 128, 1><<<dim3(NP / 128, 1), blk, 0, stream>>>(
        h1N, W2cat, nullptr, nullptr, br2, t_bf, root, nullptr, nullptr, Nn);
    gather_out_k<<<dim3((Nn * 16 + 255) / 256), blk, 0, stream>>>(
        t_bf, root, offsets, e_sw, (float*)d_out, Nn);
}

// Round 7
// 304.623 us; speedup vs baseline: 23.3846x; 1.0304x over previous
//
#include <hip/hip_runtime.h>
#include <cstddef>
#include <cstdint>

#define SCAN_B 512

using bf16x8 = __attribute__((ext_vector_type(8))) short;
using f32x4  = __attribute__((ext_vector_type(4))) float;

__device__ __forceinline__ unsigned short f2bf(float f) {
    unsigned int u = __builtin_bit_cast(unsigned int, f);
    return (unsigned short)((u + 0x7FFFu + ((u >> 16) & 1u)) >> 16);  // RNE
}
__device__ __forceinline__ float bf2f(unsigned short b) {
    unsigned int u = ((unsigned int)b) << 16;
    return __builtin_bit_cast(float, u);
}
__device__ __forceinline__ float i2f(int i) { return __builtin_bit_cast(float, i); }
__device__ __forceinline__ float u2f(unsigned int u) { return __builtin_bit_cast(float, u); }
__device__ __forceinline__ void gload_lds16(const void* g, void* l) {
    __builtin_amdgcn_global_load_lds((const __attribute__((address_space(1))) void*)g,
                                     (__attribute__((address_space(3))) void*)l, 16, 0, 0);
}

// ---------------- CSR hist (+rank) fused with f32->bf16 conversions ----------------
__global__ void hist_conv_k(const int* __restrict__ dst, int* __restrict__ counts,
                            int* __restrict__ rank, int E, int histBlocks,
                            const float* __restrict__ x, const float* __restrict__ Wr0,
                            const float* __restrict__ Wt0, const float* __restrict__ Wr1,
                            const float* __restrict__ Wt1, const float* __restrict__ Wr2,
                            const float* __restrict__ Wt2, unsigned short* __restrict__ x_bf,
                            unsigned short* __restrict__ Wr0b, unsigned short* __restrict__ Wt0b,
                            unsigned short* __restrict__ Wr1b, unsigned short* __restrict__ Wt1b,
                            unsigned short* __restrict__ Wr2b, unsigned short* __restrict__ Wt2b,
                            int n4x) {
    if ((int)blockIdx.x < histBlocks) {
        int e = blockIdx.x * 256 + threadIdx.x;
        if (e < E) rank[e] = atomicAdd(&counts[dst[e]], 1);
        return;
    }
    int j = (blockIdx.x - histBlocks) * 256 + threadIdx.x;
    const float* s;
    unsigned short* d;
    if (j < n4x) { s = x; d = x_bf; }
    else {
        j -= n4x;
        if (j < 8192) { s = Wr0; d = Wr0b; }
        else { j -= 8192;
        if (j < 8192) { s = Wt0; d = Wt0b; }
        else { j -= 8192;
        if (j < 16384) { s = Wr1; d = Wr1b; }
        else { j -= 16384;
        if (j < 16384) { s = Wt1; d = Wt1b; }
        else { j -= 16384;
        if (j < 4096) { s = Wr2; d = Wr2b; }
        else { j -= 4096;
        if (j >= 4096) return;
        s = Wt2; d = Wt2b; } } } } }
    }
    float4 v = reinterpret_cast<const float4*>(s)[j];
    ushort4 o;
    o.x = f2bf(v.x); o.y = f2bf(v.y); o.z = f2bf(v.z); o.w = f2bf(v.w);
    reinterpret_cast<ushort4*>(d)[j] = o;
}

__global__ void scan1_k(const int* __restrict__ counts, int* __restrict__ partial,
                        int* __restrict__ blocksum, int Nn) {
    __shared__ int sh[SCAN_B];
    int i = blockIdx.x * SCAN_B + threadIdx.x;
    int v = (i < Nn) ? counts[i] : 0;
    sh[threadIdx.x] = v;
    __syncthreads();
    for (int off = 1; off < SCAN_B; off <<= 1) {
        int t = (threadIdx.x >= (unsigned)off) ? sh[threadIdx.x - off] : 0;
        __syncthreads();
        sh[threadIdx.x] += t;
        __syncthreads();
    }
    if (i < Nn) partial[i] = sh[threadIdx.x];
    if (threadIdx.x == SCAN_B - 1) blocksum[blockIdx.x] = sh[threadIdx.x];
}

__global__ void scan2_k(int* __restrict__ blocksum, int nb) {
    __shared__ int sh[256];
    int v = (threadIdx.x < (unsigned)nb) ? blocksum[threadIdx.x] : 0;
    sh[threadIdx.x] = v;
    __syncthreads();
    for (int off = 1; off < 256; off <<= 1) {
        int t = (threadIdx.x >= (unsigned)off) ? sh[threadIdx.x - off] : 0;
        __syncthreads();
        sh[threadIdx.x] += t;
        __syncthreads();
    }
    if (threadIdx.x < (unsigned)nb) blocksum[threadIdx.x] = sh[threadIdx.x];
}

__global__ void scan3_k(const int* __restrict__ partial, const int* __restrict__ blocksum,
                        int* __restrict__ offsets, int Nn) {
    int i = blockIdx.x * SCAN_B + threadIdx.x;
    if (i >= Nn) return;
    int add = (blockIdx.x > 0) ? blocksum[blockIdx.x - 1] : 0;
    offsets[i + 1] = partial[i] + add;
    if (i == 0) offsets[0] = 0;
}

__global__ void fill2_k(const int* __restrict__ src, const int* __restrict__ dst,
                        const float* __restrict__ ew, const int* __restrict__ offsets,
                        const int* __restrict__ rank, int2* __restrict__ e_sw, int E) {
    int e = blockIdx.x * blockDim.x + threadIdx.x;
    if (e >= E) return;
    int d = dst[e];
    int pos = offsets[d] + rank[e];
    e_sw[pos] = make_int2(src[e], __builtin_bit_cast(int, ew[e]));
}

// ---------------- gather (CSR, bf16, f32 acc; scalar edge stream, 32-bit addr) ----------------
template<int F>
__global__ void gather_bf_k(const unsigned short* __restrict__ x, const int* __restrict__ offsets,
                            const int2* __restrict__ e_sw, unsigned short* __restrict__ agg, int Nn) {
    int wid = __builtin_amdgcn_readfirstlane((blockIdx.x * blockDim.x + threadIdx.x) >> 6);
    int lane = threadIdx.x & 63;
    if (wid >= Nn) return;
    int p = offsets[wid], end = offsets[wid + 1];
    const char* xb = (const char*)x;
    if constexpr (F == 256) {
        const unsigned loff = lane * 8u;
        float a0 = 0.f, a1 = 0.f, a2 = 0.f, a3 = 0.f;
        for (; p + 8 <= end; p += 8) {
            int2 ee[8];
            #pragma unroll
            for (int i = 0; i < 8; ++i) ee[i] = e_sw[p + i];
            uint2 vv[8];
            #pragma unroll
            for (int i = 0; i < 8; ++i)
                vv[i] = *reinterpret_cast<const uint2*>(xb + ((unsigned)ee[i].x * 512u + loff));
            #pragma unroll
            for (int i = 0; i < 8; ++i) {
                float w = i2f(ee[i].y);
                a0 += w * u2f(vv[i].x << 16); a1 += w * u2f(vv[i].x & 0xFFFF0000u);
                a2 += w * u2f(vv[i].y << 16); a3 += w * u2f(vv[i].y & 0xFFFF0000u);
            }
        }
        for (; p < end; ++p) {
            int2 e0 = e_sw[p];
            uint2 v0 = *reinterpret_cast<const uint2*>(xb + ((unsigned)e0.x * 512u + loff));
            float w = i2f(e0.y);
            a0 += w * u2f(v0.x << 16); a1 += w * u2f(v0.x & 0xFFFF0000u);
            a2 += w * u2f(v0.y << 16); a3 += w * u2f(v0.y & 0xFFFF0000u);
        }
        uint2 o;
        o.x = (unsigned)f2bf(a0) | ((unsigned)f2bf(a1) << 16);
        o.y = (unsigned)f2bf(a2) | ((unsigned)f2bf(a3) << 16);
        *reinterpret_cast<uint2*>(agg + (size_t)wid * 256 + lane * 4) = o;
    } else {  // F == 128
        const unsigned loff = lane * 4u;
        float a0 = 0.f, a1 = 0.f;
        for (; p + 8 <= end; p += 8) {
            int2 ee[8];
            #pragma unroll
            for (int i = 0; i < 8; ++i) ee[i] = e_sw[p + i];
            unsigned vv[8];
            #pragma unroll
            for (int i = 0; i < 8; ++i)
                vv[i] = *reinterpret_cast<const unsigned*>(xb + ((unsigned)ee[i].x * 256u + loff));
            #pragma unroll
            for (int i = 0; i < 8; ++i) {
                float w = i2f(ee[i].y);
                a0 += w * u2f(vv[i] << 16); a1 += w * u2f(vv[i] & 0xFFFF0000u);
            }
        }
        for (; p < end; ++p) {
            int2 e0 = e_sw[p];
            unsigned v0 = *reinterpret_cast<const unsigned*>(xb + ((unsigned)e0.x * 256u + loff));
            float w = i2f(e0.y);
            a0 += w * u2f(v0 << 16); a1 += w * u2f(v0 & 0xFFFF0000u);
        }
        unsigned o = (unsigned)f2bf(a0) | ((unsigned)f2bf(a1) << 16);
        *reinterpret_cast<unsigned*>(agg + (size_t)wid * 128 + lane * 2) = o;
    }
}

// ---- final: out[node] = root[node] + sum_e w * t[src], F=64, 16 lanes/node ----
__global__ void gather_out_k(const unsigned short* __restrict__ t, const float* __restrict__ root,
                             const int* __restrict__ offsets, const int2* __restrict__ e_sw,
                             float* __restrict__ out, int Nn) {
    int gt = blockIdx.x * blockDim.x + threadIdx.x;
    int node = gt >> 4;
    int li = gt & 15;
    if (node >= Nn) return;
    int p = offsets[node], end = offsets[node + 1];
    const char* tb = (const char*)t;
    const unsigned loff = li * 8u;
    float a0 = 0.f, a1 = 0.f, a2 = 0.f, a3 = 0.f;
    for (; p + 8 <= end; p += 8) {
        int2 ee[8];
        #pragma unroll
        for (int i = 0; i < 8; ++i) ee[i] = e_sw[p + i];
        uint2 vv[8];
        #pragma unroll
        for (int i = 0; i < 8; ++i)
            vv[i] = *reinterpret_cast<const uint2*>(tb + ((unsigned)ee[i].x * 128u + loff));
        #pragma unroll
        for (int i = 0; i < 8; ++i) {
            float w = i2f(ee[i].y);
            a0 += w * u2f(vv[i].x << 16); a1 += w * u2f(vv[i].x & 0xFFFF0000u);
            a2 += w * u2f(vv[i].y << 16); a3 += w * u2f(vv[i].y & 0xFFFF0000u);
        }
    }
    for (; p < end; ++p) {
        int2 e0 = e_sw[p];
        uint2 v0 = *reinterpret_cast<const uint2*>(tb + ((unsigned)e0.x * 128u + loff));
        float w = i2f(e0.y);
        a0 += w * u2f(v0.x << 16); a1 += w * u2f(v0.x & 0xFFFF0000u);
        a2 += w * u2f(v0.y << 16); a3 += w * u2f(v0.y & 0xFFFF0000u);
    }
    float4 r = *reinterpret_cast<const float4*>(root + (size_t)node * 64 + li * 4);
    float4 o = make_float4(r.x + a0, r.y + a1, r.z + a2, r.w + a3);
    *reinterpret_cast<float4*>(out + (size_t)node * 64 + li * 4) = o;
}

// ---------------- bf16 MFMA GEMM, 8 waves, double-buffered stage-early pipeline ----
// 512 threads, wave grid 2(rows)x4(cols); wave tile 64x32. BM=BN=128, BK=64.
// MODE 0: dual-source (A,Wa)+(X,Wb), bf16 out + fused col stats.
// MODE 1: single source; cols<64 -> t_bf (bf16), cols>=64 -> root f32 + bias.
template<int K, int O, int BM, int BN, int MODE>
__global__ __launch_bounds__(512, 4) void gemm_mfma_k(
        const unsigned short* __restrict__ A, const unsigned short* __restrict__ Wa,
        const unsigned short* __restrict__ X, const unsigned short* __restrict__ Wb,
        const float* __restrict__ bias, unsigned short* __restrict__ out_bf,
        float* __restrict__ out_f, float* __restrict__ sums, float* __restrict__ sumsq,
        int Nn) {
    constexpr int MI = BM / 32;                // 4: fragments per wave (rows)
    constexpr int OJ = BN / 64;                // 2: fragments per wave (cols)
    constexpr int KSTEPS = K / 64;
    constexpr int NT = (MODE == 0 ? 2 : 1) * KSTEPS;
    constexpr int ACH = BM / 64;               // 2 stage chunks (512 thr x 16B)
    constexpr int BCH = BN / 64;
    __shared__ unsigned short As[2][BM * 64];
    __shared__ unsigned short Bs[2][BN * 64];
    const int tid = threadIdx.x;
    const int w = tid >> 6, l = tid & 63;
    const int wr = w >> 2, wc = w & 3;
    const int lrow = l & 15, kgrp = l >> 4;
    int bx = blockIdx.x;
    bx = (bx & 7) * (gridDim.x >> 3) + (bx >> 3);   // bijective (gridDim.x % 8 == 0)
    const int m0 = bx * BM;
    const int n0 = blockIdx.y * BN;

    auto stage = [&](int buf, int t) {
        int ph = t / KSTEPS;
        int k0 = (t % KSTEPS) * 64;
        const unsigned short* Ap = (MODE == 0 && ph) ? X : A;
        const unsigned short* Wp = (MODE == 0 && ph) ? Wb : Wa;
        #pragma unroll
        for (int i = 0; i < ACH; ++i) {
            int c = i * 512 + tid;
            int row = c >> 3, slot = c & 7;
            gload_lds16(Ap + (size_t)(m0 + row) * K + k0 + ((slot ^ (row & 7)) << 3),
                        &As[buf][(i * 512 + w * 64) * 8]);
        }
        #pragma unroll
        for (int i = 0; i < BCH; ++i) {
            int c = i * 512 + tid;
            int row = c >> 3, slot = c & 7;
            gload_lds16(Wp + (size_t)(n0 + row) * K + k0 + ((slot ^ (row & 7)) << 3),
                        &Bs[buf][(i * 512 + w * 64) * 8]);
        }
    };

    f32x4 acc[MI][OJ];
    #pragma unroll
    for (int i = 0; i < MI; ++i)
        #pragma unroll
        for (int j = 0; j < OJ; ++j) {
            f32x4 z = {0.f, 0.f, 0.f, 0.f};
            acc[i][j] = z;
        }

    stage(0, 0);
    __syncthreads();
    #pragma unroll
    for (int t = 0; t < NT; ++t) {
        const int cur = t & 1;
        if (t + 1 < NT) stage(cur ^ 1, t + 1);
        #pragma unroll
        for (int ks = 0; ks < 2; ++ks) {
            bf16x8 a[MI], b[OJ];
            #pragma unroll
            for (int mi = 0; mi < MI; ++mi) {
                int row = wr * 64 + mi * 16 + lrow;
                int slot = (ks * 4 + kgrp) ^ (row & 7);
                a[mi] = *reinterpret_cast<const bf16x8*>(&As[cur][row * 64 + slot * 8]);
            }
            #pragma unroll
            for (int oj = 0; oj < OJ; ++oj) {
                int row = wc * 32 + oj * 16 + lrow;
                int slot = (ks * 4 + kgrp) ^ (row & 7);
                b[oj] = *reinterpret_cast<const bf16x8*>(&Bs[cur][row * 64 + slot * 8]);
            }
            #pragma unroll
            for (int mi = 0; mi < MI; ++mi)
                #pragma unroll
                for (int oj = 0; oj < OJ; ++oj)
                    acc[mi][oj] = __builtin_amdgcn_mfma_f32_16x16x32_bf16(
                        a[mi], b[oj], acc[mi][oj], 0, 0, 0);
        }
        __syncthreads();
    }

    if constexpr (MODE == 0) {
        #pragma unroll
        for (int oj = 0; oj < OJ; ++oj) {
            int col = n0 + wc * 32 + oj * 16 + lrow;
            float bcol = bias[col];
            float s = 0.f, q = 0.f;
            #pragma unroll
            for (int mi = 0; mi < MI; ++mi) {
                #pragma unroll
                for (int r = 0; r < 4; ++r) {
                    int row = m0 + wr * 64 + mi * 16 + kgrp * 4 + r;
                    float v = acc[mi][oj][r] + bcol;
                    if (row < Nn) {
                        out_bf[(size_t)row * O + col] = f2bf(v);
                        s += v; q += v * v;
                    }
                }
            }
            s += __shfl_xor(s, 16, 64); q += __shfl_xor(q, 16, 64);
            s += __shfl_xor(s, 32, 64); q += __shfl_xor(q, 32, 64);
            if (kgrp == 0) {
                atomicAdd(&sums[col], s);
                atomicAdd(&sumsq[col], q);
            }
        }
    } else {
        #pragma unroll
        for (int oj = 0; oj < OJ; ++oj) {
            int col = n0 + wc * 32 + oj * 16 + lrow;
            #pragma unroll
            for (int mi = 0; mi < MI; ++mi) {
                #pragma unroll
                for (int r = 0; r < 4; ++r) {
                    int row = m0 + wr * 64 + mi * 16 + kgrp * 4 + r;
                    if (row < Nn) {
                        if (col < 64)
                            out_bf[(size_t)row * 64 + col] = f2bf(acc[mi][oj][r]);
                        else
                            out_f[(size_t)row * 64 + (col - 64)] = acc[mi][oj][r] + bias[col - 64];
                    }
                }
            }
        }
    }
}

// ---------------- BN (+coef inline) + ReLU ----------------
__global__ void bn_relu_bf_k(const unsigned short* __restrict__ h, const float* __restrict__ sums,
                             const float* __restrict__ sumsq, const float* __restrict__ g,
                             const float* __restrict__ be, unsigned short* __restrict__ hb,
                             float invN, int total4) {
    int t = blockIdx.x * blockDim.x + threadIdx.x;
    if (t >= total4) return;
    int f0 = (t & 63) * 4;
    float4 sm = *reinterpret_cast<const float4*>(sums + f0);
    float4 sq = *reinterpret_cast<const float4*>(sumsq + f0);
    float4 gg = *reinterpret_cast<const float4*>(g + f0);
    float4 bb = *reinterpret_cast<const float4*>(be + f0);
    float smv[4] = {sm.x, sm.y, sm.z, sm.w};
    float sqv[4] = {sq.x, sq.y, sq.z, sq.w};
    float ggv[4] = {gg.x, gg.y, gg.z, gg.w};
    float bbv[4] = {bb.x, bb.y, bb.z, bb.w};
    ushort4 v = reinterpret_cast<const ushort4*>(h)[t];
    unsigned short vv[4] = {v.x, v.y, v.z, v.w};
    ushort4 o;
    unsigned short* op = &o.x;
    #pragma unroll
    for (int c = 0; c < 4; ++c) {
        float mu = smv[c] * invN;
        float var = sqv[c] * invN - mu * mu;
        float sc = ggv[c] * rsqrtf(var + 1e-5f);
        float sh = bbv[c] - mu * sc;
        op[c] = f2bf(fmaxf(bf2f(vv[c]) * sc + sh, 0.f));
    }
    reinterpret_cast<ushort4*>(hb)[t] = o;
}

extern "C" void kernel_launch(void* const* d_in, const int* in_sizes, int n_in,
                              void* d_out, int out_size, void* d_ws, size_t ws_size,
                              hipStream_t stream) {
    const float* x   = (const float*)d_in[0];
    const int*   ei  = (const int*)d_in[1];
    const float* ew  = (const float*)d_in[2];
    const float* Wr0 = (const float*)d_in[3];
    const float* br0 = (const float*)d_in[4];
    const float* Wt0 = (const float*)d_in[5];
    const float* g0  = (const float*)d_in[6];
    const float* be0 = (const float*)d_in[7];
    const float* Wr1 = (const float*)d_in[8];
    const float* br1 = (const float*)d_in[9];
    const float* Wt1 = (const float*)d_in[10];
    const float* g1  = (const float*)d_in[11];
    const float* be1 = (const float*)d_in[12];
    const float* Wr2 = (const float*)d_in[13];
    const float* br2 = (const float*)d_in[14];
    const float* Wt2 = (const float*)d_in[15];

    const int E  = in_sizes[2];          // 800000
    const int Nn = in_sizes[0] / 128;    // 50000
    const size_t NP = 50176;             // padded rows (NP/128 % 8 == 0)
    const int* src = ei;
    const int* dst = ei + E;

    // ---- workspace layout ----
    unsigned short* x_bf   = (unsigned short*)d_ws;        // NP*128
    unsigned short* agg_bf = x_bf + NP * 128;              // NP*256
    unsigned short* h0N    = agg_bf + NP * 256;            // NP*256
    unsigned short* h1N    = h0N + NP * 256;               // NP*256
    unsigned short* h_bf   = h1N + NP * 256;               // NP*256
    unsigned short* t_bf   = h_bf + NP * 256;              // NP*64
    unsigned short* wbf    = t_bf + NP * 64;               // 229376
    unsigned short* Wr0b = wbf;
    unsigned short* Wt0b = wbf + 32768;
    unsigned short* Wr1b = wbf + 65536;
    unsigned short* Wt1b = wbf + 131072;
    unsigned short* W2cat = wbf + 196608;                  // Wr2 | Wt2
    float* root  = (float*)(wbf + 229376);                 // NP*64 f32
    int2*  e_sw  = (int2*)(root + NP * 64);                // E
    float* stats = (float*)(e_sw + E);                     // 4096 f
    int*   counts  = (int*)(stats + 4096);                 // Nn (memset with stats)
    int*   partial = counts + Nn;                          // Nn
    int*   blocksum = partial + Nn;                        // 512
    int*   rank    = blocksum + 512;                       // E
    int*   offsets = rank + E;                             // Nn+1

    dim3 blk(256);
    const int nbScan = (Nn + SCAN_B - 1) / SCAN_B;
    const float invN = 1.0f / (float)Nn;
    const int n4x = Nn * 32;
    const int histBlocks = (E + 255) / 256;
    const int convBlocks = (n4x + 57344 + 255) / 256;

    hipMemsetAsync(stats, 0, (4096 + (size_t)Nn) * sizeof(float), stream);

    // ---- CSR hist+rank fused with bf16 conversions ----
    hist_conv_k<<<dim3(histBlocks + convBlocks), blk, 0, stream>>>(
        dst, counts, rank, E, histBlocks,
        x, Wr0, Wt0, Wr1, Wt1, Wr2, Wt2,
        x_bf, Wr0b, Wt0b, Wr1b, Wt1b, W2cat, W2cat + 16384, n4x);
    scan1_k<<<dim3(nbScan), dim3(SCAN_B), 0, stream>>>(counts, partial, blocksum, Nn);
    scan2_k<<<dim3(1), dim3(256), 0, stream>>>(blocksum, nbScan);
    scan3_k<<<dim3(nbScan), dim3(SCAN_B), 0, stream>>>(partial, blocksum, offsets, Nn);
    fill2_k<<<dim3(histBlocks), blk, 0, stream>>>(src, dst, ew, offsets, rank, e_sw, E);

    const int gatherBlocks = (Nn * 64 + 255) / 256;

    // ---------------- layer 0: K=128 -> 256 ----------------
    gather_bf_k<128><<<dim3(gatherBlocks), blk, 0, stream>>>(x_bf, offsets, e_sw, agg_bf, Nn);
    gemm_mfma_k<128, 256, 128, 128, 0><<<dim3(NP / 128, 2), dim3(512), 0, stream>>>(
        agg_bf, Wr0b, x_bf, Wt0b, br0, h_bf, nullptr, stats + 0, stats + 256, Nn);
    bn_relu_bf_k<<<dim3((Nn * 64 + 255) / 256), blk, 0, stream>>>(
        h_bf, stats + 0, stats + 256, g0, be0, h0N, invN, Nn * 64);

    // ---------------- layer 1: K=256 -> 256 ----------------
    gather_bf_k<256><<<dim3(gatherBlocks), blk, 0, stream>>>(h0N, offsets, e_sw, agg_bf, Nn);
    gemm_mfma_k<256, 256, 128, 128, 0><<<dim3(NP / 128, 2), dim3(512), 0, stream>>>(
        agg_bf, Wr1b, h0N, Wt1b, br1, h_bf, nullptr, stats + 1024, stats + 1280, Nn);
    bn_relu_bf_k<<<dim3((Nn * 64 + 255) / 256), blk, 0, stream>>>(
        h_bf, stats + 1024, stats + 1280, g1, be1, h1N, invN, Nn * 64);

    // ---------------- layer 2: transform-first ----------------
    gemm_mfma_k<256, 128, 128, 128, 1><<<dim3(NP / 128, 1), dim3(512), 0, stream>>>(
        h1N, W2cat, nullptr, nullptr, br2, t_bf, root, nullptr, nullptr, Nn);
    gather_out_k<<<dim3((Nn * 16 + 255) / 256), blk, 0, stream>>>(
        t_bf, root, offsets, e_sw, (float*)d_out, Nn);
}